// Round 9
// baseline (413.369 us; speedup 1.0000x reference)
//
#include <hip/hip_runtime.h>
#include <hip/hip_bf16.h>

#define NN 32768
#define DEG 32
#define FF 128
#define OO 128
#define MB 32   // nodes per block

typedef __attribute__((ext_vector_type(8))) short bfrag;   // 8 bf16 (MFMA A/B operand)
typedef __attribute__((ext_vector_type(4))) float f32x4;   // MFMA C/D

#define K1 1.4426950408889634f
#define K2 2.8853900817779268f

// cheap fp32->bf16: round-half-up == RNE except exact ties (prob 2^-16)
__device__ __forceinline__ unsigned short b16(float x) {
    unsigned u = __float_as_uint(x) + 0x8000u;
    return (unsigned short)(u >> 16);
}
__device__ __forceinline__ bfrag pack8(float4 a, float4 b) {
    bfrag r;
    r[0] = (short)b16(a.x); r[1] = (short)b16(a.y); r[2] = (short)b16(a.z); r[3] = (short)b16(a.w);
    r[4] = (short)b16(b.x); r[5] = (short)b16(b.y); r[6] = (short)b16(b.z); r[7] = (short)b16(b.w);
    return r;
}

// async global->LDS, 16B per lane, dest = wave-uniform base + lane*16
__device__ __forceinline__ void gload16(const void* g, void* l) {
    __builtin_amdgcn_global_load_lds(
        (const __attribute__((address_space(1))) unsigned int*)g,
        (__attribute__((address_space(3))) unsigned int*)l, 16, 0, 0);
}

// -------- prep: weights/biases to bf16 (fold 1/deg into W2, combine biases) --------
__global__ void prep_weights(const float* __restrict__ wih, const float* __restrict__ whh,
                             const float* __restrict__ b_ih, const float* __restrict__ b_hh,
                             const float* __restrict__ w1, const float* __restrict__ b1,
                             const float* __restrict__ w2, const float* __restrict__ b2,
                             short* __restrict__ wihb, short* __restrict__ whhb,
                             short* __restrict__ w1b, short* __restrict__ w2b,
                             float* __restrict__ biasg, float* __restrict__ biaso)
{
    int i = blockIdx.x * blockDim.x + threadIdx.x;
    if (i < 512 * 128) { wihb[i] = (short)b16(wih[i]); whhb[i] = (short)b16(whh[i]); }
    if (i < 128 * 128) { w1b[i] = (short)b16(w1[i]); w2b[i] = (short)b16(w2[i] * 0.03125f); }
    if (i < 512) biasg[i] = b_ih[i] + b_hh[i];
    if (i < 128) biaso[i] = b1[i] + b2[i];
}

// -------- prep: feat fp32 -> bf16 (8 elements / thread) --------
__global__ void prep_feat(const float* __restrict__ f, short* __restrict__ fb) {
    int i = blockIdx.x * blockDim.x + threadIdx.x;       // 524288 threads
    const float4* p = reinterpret_cast<const float4*>(f) + (size_t)i * 2;
    float4 a = p[0], b = p[1];
    *reinterpret_cast<bfrag*>(fb + (size_t)i * 8) = pack8(a, b);
}

template<bool BF16F>
__device__ __forceinline__ bfrag load_row8(const float* __restrict__ ff, const short* __restrict__ fb,
                                           int node, int cs) {
    if (BF16F) {
        return *reinterpret_cast<const bfrag*>(fb + node * FF + cs * 8);
    } else {
        const float4* p = reinterpret_cast<const float4*>(ff + node * FF + cs * 8);
        return pack8(p[0], p[1]);
    }
}

// ====================== REAL KERNEL (R4 structure, reduced-trans act) ======================
template<bool BF16F>
__global__ __launch_bounds__(512, 2)
void sage_lstm_kernel(const float* __restrict__ featf, const short* __restrict__ featb,
                      const int* __restrict__ nidx,
                      const short* __restrict__ wihb, const short* __restrict__ whhb,
                      const short* __restrict__ w1b, const short* __restrict__ w2b,
                      const float* __restrict__ biasg, const float* __restrict__ biaso,
                      float* __restrict__ out)
{
    __shared__ short xbuf[2][MB * 128];
    __shared__ short hbuf[2][MB * 128];
    __shared__ int   idx_s[MB * DEG];

    const int tid  = (int)threadIdx.x;
    const int lane = tid & 63;
    const int wave = tid >> 6;
    const int n0   = (int)blockIdx.x * MB;

    const int srow = tid >> 4;
    const int cs   = tid & 15;

    idx_s[tid]       = nidx[n0 * DEG + tid];
    idx_s[512 + tid] = nidx[n0 * DEG + 512 + tid];
    {   bfrag z; for (int j = 0; j < 8; ++j) z[j] = 0;
        reinterpret_cast<bfrag*>(hbuf[0])[tid] = z; }

    const int colw = wave * 16 + (lane & 15);
    bfrag wih[4][4], whh[4][4];
#pragma unroll
    for (int g = 0; g < 4; ++g) {
        const short* pih = wihb + (g * 128 + colw) * FF + (lane >> 4) * 8;
        const short* phh = whhb + (g * 128 + colw) * FF + (lane >> 4) * 8;
#pragma unroll
        for (int kt = 0; kt < 4; ++kt) {
            wih[g][kt] = *reinterpret_cast<const bfrag*>(pih + kt * 32);
            whh[g][kt] = *reinterpret_cast<const bfrag*>(phh + kt * 32);
        }
    }
    const float bi = biasg[colw];
    const float bf = biasg[128 + colw];
    const float bg = biasg[256 + colw];
    const float bo = biasg[384 + colw];
    const f32x4 bvi = {bi, bi, bi, bi};
    const f32x4 bvf = {bf, bf, bf, bf};
    const f32x4 bvg = {bg, bg, bg, bg};
    const f32x4 bvo = {bo, bo, bo, bo};

    __syncthreads();

    {
        bfrag v = load_row8<BF16F>(featf, featb, idx_s[srow * DEG], cs);
        int sb = (srow * 256 + cs * 16) ^ ((srow & 7) << 4);
        *reinterpret_cast<bfrag*>(reinterpret_cast<char*>(xbuf[0]) + sb) = v;
    }
    __syncthreads();

    const int arow = lane & 15;
    const int asub = (lane >> 4) * 16;
    const int hr0  = (lane >> 4) * 4;
    const int swz  = (arow & 7) << 4;

    f32x4 p0i, p0f, p0g, p0o, p1i, p1f, p1g, p1o;
    {
        char* x0p = reinterpret_cast<char*>(xbuf[0]);
        bfrag xa[4];
#pragma unroll
        for (int kt = 0; kt < 4; ++kt)
            xa[kt] = *reinterpret_cast<const bfrag*>(x0p + ((arow * 256 + kt * 64 + asub) ^ swz));
        p0i = bvi; p0f = bvf; p0g = bvg; p0o = bvo;
#pragma unroll
        for (int kt = 0; kt < 4; ++kt) {
            p0i = __builtin_amdgcn_mfma_f32_16x16x32_bf16(xa[kt], wih[0][kt], p0i, 0, 0, 0);
            p0f = __builtin_amdgcn_mfma_f32_16x16x32_bf16(xa[kt], wih[1][kt], p0f, 0, 0, 0);
            p0g = __builtin_amdgcn_mfma_f32_16x16x32_bf16(xa[kt], wih[2][kt], p0g, 0, 0, 0);
            p0o = __builtin_amdgcn_mfma_f32_16x16x32_bf16(xa[kt], wih[3][kt], p0o, 0, 0, 0);
        }
#pragma unroll
        for (int kt = 0; kt < 4; ++kt)
            xa[kt] = *reinterpret_cast<const bfrag*>(x0p + (((16 + arow) * 256 + kt * 64 + asub) ^ swz));
        p1i = bvi; p1f = bvf; p1g = bvg; p1o = bvo;
#pragma unroll
        for (int kt = 0; kt < 4; ++kt) {
            p1i = __builtin_amdgcn_mfma_f32_16x16x32_bf16(xa[kt], wih[0][kt], p1i, 0, 0, 0);
            p1f = __builtin_amdgcn_mfma_f32_16x16x32_bf16(xa[kt], wih[1][kt], p1f, 0, 0, 0);
            p1g = __builtin_amdgcn_mfma_f32_16x16x32_bf16(xa[kt], wih[2][kt], p1g, 0, 0, 0);
            p1o = __builtin_amdgcn_mfma_f32_16x16x32_bf16(xa[kt], wih[3][kt], p1o, 0, 0, 0);
        }
    }
    {
        bfrag v = load_row8<BF16F>(featf, featb, idx_s[srow * DEG + 1], cs);
        int sb = (srow * 256 + cs * 16) ^ ((srow & 7) << 4);
        *reinterpret_cast<bfrag*>(reinterpret_cast<char*>(xbuf[1]) + sb) = v;
    }
    __syncthreads();

    const f32x4 zz = {0.f, 0.f, 0.f, 0.f};
    f32x4 cs0 = zz, cs1 = zz;

    // reduced-trans activation: 5 exp2 + 3 rcp per r
    auto actw = [&](f32x4& gi, f32x4& gf, f32x4& gg, f32x4& go,
                    f32x4& cst, char* hnxt, int rt) {
#pragma unroll
        for (int r = 0; r < 4; ++r) {
            float av = __builtin_amdgcn_exp2f(-K1 * gi[r]);
            float bv = __builtin_amdgcn_exp2f(K2 * fminf(gg[r], 40.0f));
            float dv = __builtin_amdgcn_exp2f(-K1 * gf[r]);
            float ev = __builtin_amdgcn_exp2f(-K1 * go[r]);
            float t1 = __builtin_amdgcn_rcpf((1.0f + av) * (1.0f + bv));
            float t2 = __builtin_amdgcn_rcpf(1.0f + dv);
            float c  = fmaf(cst[r], t2, (bv - 1.0f) * t1);
            cst[r] = c;
            float uv = __builtin_amdgcn_exp2f(K2 * c);
            float t3 = __builtin_amdgcn_rcpf((1.0f + ev) * (1.0f + uv));
            float h  = (uv - 1.0f) * t3;
            int hrow = rt * 16 + hr0 + r;
            int hb   = (hrow * 256 + colw * 2) ^ ((hrow & 7) << 4);
            *reinterpret_cast<unsigned short*>(hnxt + hb) = b16(h);
        }
    };

#pragma unroll 2
    for (int t = 0; t < DEG; ++t) {
        const int cur = t & 1;
        char* hcur = reinterpret_cast<char*>(hbuf[cur]);
        char* hnxt = reinterpret_cast<char*>(hbuf[cur ^ 1]);
        char* xrd  = reinterpret_cast<char*>(xbuf[cur ^ 1]);
        char* xwr  = reinterpret_cast<char*>(xbuf[cur]);

        bfrag pre2;
        if (t < DEG - 2) pre2 = load_row8<BF16F>(featf, featb, idx_s[srow * DEG + t + 2], cs);

        {
            bfrag ha[4];
#pragma unroll
            for (int kt = 0; kt < 4; ++kt)
                ha[kt] = *reinterpret_cast<const bfrag*>(hcur + ((arow * 256 + kt * 64 + asub) ^ swz));
            f32x4 gi = p0i, gf = p0f, gg = p0g, go = p0o;
#pragma unroll
            for (int kt = 0; kt < 4; ++kt) {
                gi = __builtin_amdgcn_mfma_f32_16x16x32_bf16(ha[kt], whh[0][kt], gi, 0, 0, 0);
                gf = __builtin_amdgcn_mfma_f32_16x16x32_bf16(ha[kt], whh[1][kt], gf, 0, 0, 0);
                gg = __builtin_amdgcn_mfma_f32_16x16x32_bf16(ha[kt], whh[2][kt], gg, 0, 0, 0);
                go = __builtin_amdgcn_mfma_f32_16x16x32_bf16(ha[kt], whh[3][kt], go, 0, 0, 0);
            }
            if (t < DEG - 1) {
                bfrag xn[4];
#pragma unroll
                for (int kt = 0; kt < 4; ++kt)
                    xn[kt] = *reinterpret_cast<const bfrag*>(xrd + ((arow * 256 + kt * 64 + asub) ^ swz));
                p0i = bvi; p0f = bvf; p0g = bvg; p0o = bvo;
#pragma unroll
                for (int kt = 0; kt < 4; ++kt) {
                    p0i = __builtin_amdgcn_mfma_f32_16x16x32_bf16(xn[kt], wih[0][kt], p0i, 0, 0, 0);
                    p0f = __builtin_amdgcn_mfma_f32_16x16x32_bf16(xn[kt], wih[1][kt], p0f, 0, 0, 0);
                    p0g = __builtin_amdgcn_mfma_f32_16x16x32_bf16(xn[kt], wih[2][kt], p0g, 0, 0, 0);
                    p0o = __builtin_amdgcn_mfma_f32_16x16x32_bf16(xn[kt], wih[3][kt], p0o, 0, 0, 0);
                }
            }
            actw(gi, gf, gg, go, cs0, hnxt, 0);
        }
        {
            bfrag ha[4];
#pragma unroll
            for (int kt = 0; kt < 4; ++kt)
                ha[kt] = *reinterpret_cast<const bfrag*>(hcur + (((16 + arow) * 256 + kt * 64 + asub) ^ swz));
            f32x4 gi = p1i, gf = p1f, gg = p1g, go = p1o;
#pragma unroll
            for (int kt = 0; kt < 4; ++kt) {
                gi = __builtin_amdgcn_mfma_f32_16x16x32_bf16(ha[kt], whh[0][kt], gi, 0, 0, 0);
                gf = __builtin_amdgcn_mfma_f32_16x16x32_bf16(ha[kt], whh[1][kt], gf, 0, 0, 0);
                gg = __builtin_amdgcn_mfma_f32_16x16x32_bf16(ha[kt], whh[2][kt], gg, 0, 0, 0);
                go = __builtin_amdgcn_mfma_f32_16x16x32_bf16(ha[kt], whh[3][kt], go, 0, 0, 0);
            }
            if (t < DEG - 1) {
                bfrag xn[4];
#pragma unroll
                for (int kt = 0; kt < 4; ++kt)
                    xn[kt] = *reinterpret_cast<const bfrag*>(xrd + (((16 + arow) * 256 + kt * 64 + asub) ^ swz));
                p1i = bvi; p1f = bvf; p1g = bvg; p1o = bvo;
#pragma unroll
                for (int kt = 0; kt < 4; ++kt) {
                    p1i = __builtin_amdgcn_mfma_f32_16x16x32_bf16(xn[kt], wih[0][kt], p1i, 0, 0, 0);
                    p1f = __builtin_amdgcn_mfma_f32_16x16x32_bf16(xn[kt], wih[1][kt], p1f, 0, 0, 0);
                    p1g = __builtin_amdgcn_mfma_f32_16x16x32_bf16(xn[kt], wih[2][kt], p1g, 0, 0, 0);
                    p1o = __builtin_amdgcn_mfma_f32_16x16x32_bf16(xn[kt], wih[3][kt], p1o, 0, 0, 0);
                }
            }
            actw(gi, gf, gg, go, cs1, hnxt, 1);
        }

        if (t < DEG - 2) {
            int sb = (srow * 256 + cs * 16) ^ ((srow & 7) << 4);
            *reinterpret_cast<bfrag*>(xwr + sb) = pre2;
        }
        __syncthreads();
    }

    // epilogue
    {
        bfrag v = load_row8<BF16F>(featf, featb, n0 + srow, cs);
        int sb = (srow * 256 + cs * 16) ^ ((srow & 7) << 4);
        *reinterpret_cast<bfrag*>(reinterpret_cast<char*>(xbuf[0]) + sb) = v;
    }
    __syncthreads();

    char* const x0p = reinterpret_cast<char*>(xbuf[0]);
    char* const h0p = reinterpret_cast<char*>(hbuf[0]);
    bfrag w1f[4], w2f[4];
#pragma unroll
    for (int kt = 0; kt < 4; ++kt) {
        w1f[kt] = *reinterpret_cast<const bfrag*>(w1b + colw * FF + kt * 32 + (lane >> 4) * 8);
        w2f[kt] = *reinterpret_cast<const bfrag*>(w2b + colw * FF + kt * 32 + (lane >> 4) * 8);
    }
    const float bb = biaso[colw];
#pragma unroll
    for (int rt = 0; rt < 2; ++rt) {
        const int rowr = rt * 16 + arow;
        bfrag fa[4], hfa[4];
#pragma unroll
        for (int kt = 0; kt < 4; ++kt) {
            int byte = (rowr * 256 + kt * 64 + asub) ^ swz;
            fa[kt]  = *reinterpret_cast<const bfrag*>(x0p + byte);
            hfa[kt] = *reinterpret_cast<const bfrag*>(h0p + byte);
        }
        f32x4 acc = {0.f, 0.f, 0.f, 0.f};
#pragma unroll
        for (int kt = 0; kt < 4; ++kt) {
            acc = __builtin_amdgcn_mfma_f32_16x16x32_bf16(fa[kt],  w1f[kt], acc, 0, 0, 0);
            acc = __builtin_amdgcn_mfma_f32_16x16x32_bf16(hfa[kt], w2f[kt], acc, 0, 0, 0);
        }
#pragma unroll
        for (int r = 0; r < 4; ++r) {
            int orow = n0 + rt * 16 + hr0 + r;
            out[orow * OO + colw] = acc[r] + bb;
        }
    }
}

// ====================== PROBE A: structure floor (act stripped) ======================
__global__ __launch_bounds__(512, 2)
void probe_floor(const short* __restrict__ featb, const int* __restrict__ nidx,
                 const short* __restrict__ wihb, const short* __restrict__ whhb,
                 const float* __restrict__ biasg, short* __restrict__ sink)
{
    __shared__ short xbuf[2][MB * 128];
    __shared__ short hbuf[2][MB * 128];
    __shared__ int   idx_s[MB * DEG];

    const int tid  = (int)threadIdx.x;
    const int lane = tid & 63;
    const int wave = tid >> 6;
    const int n0   = (int)blockIdx.x * MB;
    const int srow = tid >> 4;
    const int cs   = tid & 15;

    idx_s[tid]       = nidx[n0 * DEG + tid];
    idx_s[512 + tid] = nidx[n0 * DEG + 512 + tid];
    {   bfrag z; for (int j = 0; j < 8; ++j) z[j] = 0;
        reinterpret_cast<bfrag*>(hbuf[0])[tid] = z; }

    const int colw = wave * 16 + (lane & 15);
    bfrag wih[4][4], whh[4][4];
#pragma unroll
    for (int g = 0; g < 4; ++g) {
        const short* pih = wihb + (g * 128 + colw) * FF + (lane >> 4) * 8;
        const short* phh = whhb + (g * 128 + colw) * FF + (lane >> 4) * 8;
#pragma unroll
        for (int kt = 0; kt < 4; ++kt) {
            wih[g][kt] = *reinterpret_cast<const bfrag*>(pih + kt * 32);
            whh[g][kt] = *reinterpret_cast<const bfrag*>(phh + kt * 32);
        }
    }
    const float bi = biasg[colw];
    const f32x4 bvi = {bi, bi, bi, bi};

    __syncthreads();
    {
        bfrag v = *reinterpret_cast<const bfrag*>(featb + idx_s[srow * DEG] * FF + cs * 8);
        int sb = (srow * 256 + cs * 16) ^ ((srow & 7) << 4);
        *reinterpret_cast<bfrag*>(reinterpret_cast<char*>(xbuf[0]) + sb) = v;
    }
    __syncthreads();

    const int arow = lane & 15;
    const int asub = (lane >> 4) * 16;
    const int hr0  = (lane >> 4) * 4;
    const int swz  = (arow & 7) << 4;

    auto mm4a = [&](const char* p, int rbase, const bfrag (&W)[4][4],
                    f32x4& vi, f32x4& vf, f32x4& vg, f32x4& vo) {
        bfrag a[4];
#pragma unroll
        for (int kt = 0; kt < 4; ++kt)
            a[kt] = *reinterpret_cast<const bfrag*>(p + ((rbase * 256 + kt * 64 + asub) ^ swz));
#pragma unroll
        for (int kt = 0; kt < 4; ++kt) {
            vi = __builtin_amdgcn_mfma_f32_16x16x32_bf16(a[kt], W[0][kt], vi, 0, 0, 0);
            vf = __builtin_amdgcn_mfma_f32_16x16x32_bf16(a[kt], W[1][kt], vf, 0, 0, 0);
            vg = __builtin_amdgcn_mfma_f32_16x16x32_bf16(a[kt], W[2][kt], vg, 0, 0, 0);
            vo = __builtin_amdgcn_mfma_f32_16x16x32_bf16(a[kt], W[3][kt], vo, 0, 0, 0);
        }
    };

    f32x4 p0i = bvi, p0f = bvi, p0g = bvi, p0o = bvi;
    f32x4 p1i = bvi, p1f = bvi, p1g = bvi, p1o = bvi;
    mm4a(reinterpret_cast<char*>(xbuf[0]), arow, wih, p0i, p0f, p0g, p0o);
    mm4a(reinterpret_cast<char*>(xbuf[0]), 16 + arow, wih, p1i, p1f, p1g, p1o);
    {
        bfrag v = *reinterpret_cast<const bfrag*>(featb + idx_s[srow * DEG + 1] * FF + cs * 8);
        int sb = (srow * 256 + cs * 16) ^ ((srow & 7) << 4);
        *reinterpret_cast<bfrag*>(reinterpret_cast<char*>(xbuf[1]) + sb) = v;
    }
    __syncthreads();

#pragma unroll 2
    for (int t = 0; t < DEG; ++t) {
        const int cur = t & 1;
        char* hcur = reinterpret_cast<char*>(hbuf[cur]);
        char* hnxt = reinterpret_cast<char*>(hbuf[cur ^ 1]);
        char* xrd  = reinterpret_cast<char*>(xbuf[cur ^ 1]);
        char* xwr  = reinterpret_cast<char*>(xbuf[cur]);

        bfrag pre2;
        if (t < DEG - 2)
            pre2 = *reinterpret_cast<const bfrag*>(featb + idx_s[srow * DEG + t + 2] * FF + cs * 8);

        {
            f32x4 gi = p0i, gf = p0f, gg = p0g, go = p0o;
            mm4a(hcur, arow, whh, gi, gf, gg, go);
            if (t < DEG - 1) {
                p0i = bvi; p0f = bvi; p0g = bvi; p0o = bvi;
                mm4a(xrd, arow, wih, p0i, p0f, p0g, p0o);
            }
#pragma unroll
            for (int r = 0; r < 4; ++r) {     // act stubbed: 2-op write, keeps deps live
                float h = 0.0625f * ((gi[r] + gf[r]) + (gg[r] + go[r]));
                int hrow = hr0 + r;
                int hb = (hrow * 256 + colw * 2) ^ ((hrow & 7) << 4);
                *reinterpret_cast<unsigned short*>(hnxt + hb) = b16(h);
            }
        }
        {
            f32x4 gi = p1i, gf = p1f, gg = p1g, go = p1o;
            mm4a(hcur, 16 + arow, whh, gi, gf, gg, go);
            if (t < DEG - 1) {
                p1i = bvi; p1f = bvi; p1g = bvi; p1o = bvi;
                mm4a(xrd, 16 + arow, wih, p1i, p1f, p1g, p1o);
            }
#pragma unroll
            for (int r = 0; r < 4; ++r) {
                float h = 0.0625f * ((gi[r] + gf[r]) + (gg[r] + go[r]));
                int hrow = 16 + hr0 + r;
                int hb = (hrow * 256 + colw * 2) ^ ((hrow & 7) << 4);
                *reinterpret_cast<unsigned short*>(hnxt + hb) = b16(h);
            }
        }

        if (t < DEG - 2) {
            int sb = (srow * 256 + cs * 16) ^ ((srow & 7) << 4);
            *reinterpret_cast<bfrag*>(xwr + sb) = pre2;
        }
        __syncthreads();
    }
    float s = p0i[0] + p0f[1] + p0g[2] + p0o[3] + p1i[0] + p1f[1] + p1g[2] + p1o[3]
            + (float)hbuf[0][tid];
    if (lane == 0) sink[blockIdx.x * 8 + wave] = (short)b16(s);
}

// ====================== PROBE B: pure MFMA-cluster ceiling ======================
__global__ __launch_bounds__(512, 2)
void probe_mfma(const short* __restrict__ wihb, const short* __restrict__ whhb,
                short* __restrict__ sink)
{
    __shared__ char lds[32768];
    const int tid  = (int)threadIdx.x;
    const int lane = tid & 63;
    const int wave = tid >> 6;

    {   bfrag z; for (int j = 0; j < 8; ++j) z[j] = 0;
        *reinterpret_cast<bfrag*>(lds + tid * 16)         = z;
        *reinterpret_cast<bfrag*>(lds + 8192  + tid * 16) = z;
        *reinterpret_cast<bfrag*>(lds + 16384 + tid * 16) = z;
        *reinterpret_cast<bfrag*>(lds + 24576 + tid * 16) = z; }

    const int colw = wave * 16 + (lane & 15);
    bfrag wih[4][4], whh[4][4];
#pragma unroll
    for (int g = 0; g < 4; ++g) {
        const short* pih = wihb + (g * 128 + colw) * FF + (lane >> 4) * 8;
        const short* phh = whhb + (g * 128 + colw) * FF + (lane >> 4) * 8;
#pragma unroll
        for (int kt = 0; kt < 4; ++kt) {
            wih[g][kt] = *reinterpret_cast<const bfrag*>(pih + kt * 32);
            whh[g][kt] = *reinterpret_cast<const bfrag*>(phh + kt * 32);
        }
    }
    __syncthreads();

    const int arow = lane & 15;
    const int asub = (lane >> 4) * 16;
    const int swz  = (arow & 7) << 4;

    auto mm4a = [&](const char* p, int rbase, const bfrag (&W)[4][4],
                    f32x4& vi, f32x4& vf, f32x4& vg, f32x4& vo) {
        bfrag a[4];
#pragma unroll
        for (int kt = 0; kt < 4; ++kt)
            a[kt] = *reinterpret_cast<const bfrag*>(p + ((rbase * 256 + kt * 64 + asub) ^ swz));
#pragma unroll
        for (int kt = 0; kt < 4; ++kt) {
            vi = __builtin_amdgcn_mfma_f32_16x16x32_bf16(a[kt], W[0][kt], vi, 0, 0, 0);
            vf = __builtin_amdgcn_mfma_f32_16x16x32_bf16(a[kt], W[1][kt], vf, 0, 0, 0);
            vg = __builtin_amdgcn_mfma_f32_16x16x32_bf16(a[kt], W[2][kt], vg, 0, 0, 0);
            vo = __builtin_amdgcn_mfma_f32_16x16x32_bf16(a[kt], W[3][kt], vo, 0, 0, 0);
        }
    };

    const f32x4 zz = {0.f, 0.f, 0.f, 0.f};
    f32x4 Gi0 = zz, Gf0 = zz, Gg0 = zz, Go0 = zz;
    f32x4 Gi1 = zz, Gf1 = zz, Gg1 = zz, Go1 = zz;
    char* const h0 = lds + 16384;

#pragma unroll 1
    for (int tt = 0; tt < DEG; tt += 2) {
        // 64 MFMAs per wave per "step", same cluster shape as the real kernel
        mm4a(h0,  arow,      whh, Gi0, Gf0, Gg0, Go0);
        mm4a(lds, arow,      wih, Gi0, Gf0, Gg0, Go0);
        mm4a(h0,  16 + arow, whh, Gi1, Gf1, Gg1, Go1);
        mm4a(lds, 16 + arow, wih, Gi1, Gf1, Gg1, Go1);
        mm4a(h0,  arow,      whh, Gi0, Gf0, Gg0, Go0);
        mm4a(lds + 8192, arow,      wih, Gi0, Gf0, Gg0, Go0);
        mm4a(h0,  16 + arow, whh, Gi1, Gf1, Gg1, Go1);
        mm4a(lds + 8192, 16 + arow, wih, Gi1, Gf1, Gg1, Go1);
    }
    float s = Gi0[0] + Gf0[1] + Gg0[2] + Go0[3] + Gi1[0] + Gf1[1] + Gg1[2] + Go1[3];
    if (lane == 0) sink[blockIdx.x * 8 + wave] = (short)b16(s);
}

extern "C" void kernel_launch(void* const* d_in, const int* in_sizes, int n_in,
                              void* d_out, int out_size, void* d_ws, size_t ws_size,
                              hipStream_t stream)
{
    const float* feat = (const float*)d_in[0];
    const int*   nidx = (const int*)d_in[1];
    const float* W_ih = (const float*)d_in[2];
    const float* W_hh = (const float*)d_in[3];
    const float* b_ih = (const float*)d_in[4];
    const float* b_hh = (const float*)d_in[5];
    const float* W1   = (const float*)d_in[6];
    const float* b1   = (const float*)d_in[7];
    const float* W2   = (const float*)d_in[8];
    const float* b2   = (const float*)d_in[9];
    float* out = (float*)d_out;

    char* ws = (char*)d_ws;
    short* wihb  = (short*)(ws);             // 131072 B
    short* whhb  = (short*)(ws + 131072);    // 131072 B
    short* w1b   = (short*)(ws + 262144);    // 32768 B
    short* w2b   = (short*)(ws + 294912);    // 32768 B
    float* biasg = (float*)(ws + 327680);    // 2048 B
    float* biaso = (float*)(ws + 329728);    // 512 B
    short* featb = (short*)(ws + 330240);    // 8388608 B
    short* sink  = (short*)(ws + 330240 + 8388608);   // 8192 B probe scratch

    const size_t need  = 330240 + (size_t)NN * FF * 2;
    const size_t need2 = need + 8192;
    const bool bf = ws_size >= need;
    const bool pr = ws_size >= need2;

    prep_weights<<<256, 256, 0, stream>>>(W_ih, W_hh, b_ih, b_hh, W1, b1, W2, b2,
                                          wihb, whhb, w1b, w2b, biasg, biaso);
    if (bf) {
        prep_feat<<<2048, 256, 0, stream>>>(feat, featb);
        sage_lstm_kernel<true><<<NN / MB, 512, 0, stream>>>(feat, featb, nidx, wihb, whhb,
                                                            w1b, w2b, biasg, biaso, out);
        if (pr) {
            probe_floor<<<256, 512, 0, stream>>>(featb, nidx, wihb, whhb, biasg, sink);
            probe_mfma<<<256, 512, 0, stream>>>(wihb, whhb, sink);
        }
    } else {
        sage_lstm_kernel<false><<<NN / MB, 512, 0, stream>>>(feat, featb, nidx, wihb, whhb,
                                                             w1b, w2b, biasg, biaso, out);
    }
}

// Round 10
// 359.420 us; speedup vs baseline: 1.1501x; 1.1501x over previous
//
#include <hip/hip_runtime.h>
#include <hip/hip_bf16.h>

#define NN 32768
#define DEG 32
#define FF 128
#define OO 128
#define MB 32

#define K1 1.4426950408889634f
#define K2 2.8853900817779268f

// main-kernel LDS layout (bytes)
#define PPITCH 1056          // padded P row: 512 bf16 + 16 pad shorts
#define P0OFF 0
#define P1OFF 33792          // 32*PPITCH
#define H0OFF 67584
#define H1OFF 75776          // total 83968

typedef __attribute__((ext_vector_type(8))) short bfrag;
typedef __attribute__((ext_vector_type(4))) float f32x4;

__device__ __forceinline__ unsigned short b16(float x) {
    unsigned u = __float_as_uint(x) + 0x8000u;
    return (unsigned short)(u >> 16);
}
__device__ __forceinline__ float bf2f(unsigned short u) {
    return __uint_as_float((unsigned)u << 16);
}
__device__ __forceinline__ bfrag pack8(float4 a, float4 b) {
    bfrag r;
    r[0] = (short)b16(a.x); r[1] = (short)b16(a.y); r[2] = (short)b16(a.z); r[3] = (short)b16(a.w);
    r[4] = (short)b16(b.x); r[5] = (short)b16(b.y); r[6] = (short)b16(b.z); r[7] = (short)b16(b.w);
    return r;
}
__device__ __forceinline__ void gload16(const void* g, void* l) {
    __builtin_amdgcn_global_load_lds(
        (const __attribute__((address_space(1))) unsigned int*)g,
        (__attribute__((address_space(3))) unsigned int*)l, 16, 0, 0);
}

// -------- prep: weights/biases to bf16 (fold 1/deg into W2, combine biases) --------
__global__ void prep_weights(const float* __restrict__ wih, const float* __restrict__ whh,
                             const float* __restrict__ b_ih, const float* __restrict__ b_hh,
                             const float* __restrict__ w1, const float* __restrict__ b1,
                             const float* __restrict__ w2, const float* __restrict__ b2,
                             short* __restrict__ wihb, short* __restrict__ whhb,
                             short* __restrict__ w1b, short* __restrict__ w2b,
                             float* __restrict__ biasg, float* __restrict__ biaso)
{
    int i = blockIdx.x * blockDim.x + threadIdx.x;
    if (i < 512 * 128) { wihb[i] = (short)b16(wih[i]); whhb[i] = (short)b16(whh[i]); }
    if (i < 128 * 128) { w1b[i] = (short)b16(w1[i]); w2b[i] = (short)b16(w2[i] * 0.03125f); }
    if (i < 512) biasg[i] = b_ih[i] + b_hh[i];
    if (i < 128) biaso[i] = b1[i] + b2[i];
}

// -------- XP pre-GEMM: XP[n][g*128+c] = bias[g*128+c] + feat[n]@W_ih[g*128+c]^T (bf16) --------
__global__ __launch_bounds__(512, 2)
void xp_gemm(const float* __restrict__ feat, const short* __restrict__ wihb,
             const float* __restrict__ biasg, unsigned short* __restrict__ xp)
{
    __shared__ short xt[MB * 128];

    const int tid  = (int)threadIdx.x;
    const int lane = tid & 63;
    const int wave = tid >> 6;
    const int n0   = (int)blockIdx.x * MB;
    const int srow = tid >> 4;
    const int cs   = tid & 15;

    {   const float4* p = reinterpret_cast<const float4*>(feat + (n0 + srow) * FF + cs * 8);
        int sb = (srow * 256 + cs * 16) ^ ((srow & 7) << 4);
        *reinterpret_cast<bfrag*>(reinterpret_cast<char*>(xt) + sb) = pack8(p[0], p[1]); }

    const int colw = wave * 16 + (lane & 15);
    bfrag wih[4][4];
#pragma unroll
    for (int g = 0; g < 4; ++g) {
        const short* pih = wihb + (g * 128 + colw) * FF + (lane >> 4) * 8;
#pragma unroll
        for (int kt = 0; kt < 4; ++kt)
            wih[g][kt] = *reinterpret_cast<const bfrag*>(pih + kt * 32);
    }
    float bg4[4];
#pragma unroll
    for (int g = 0; g < 4; ++g) bg4[g] = biasg[g * 128 + colw];

    __syncthreads();

    const int arow = lane & 15;
    const int asub = (lane >> 4) * 16;
    const int hr0  = (lane >> 4) * 4;
    const int swz  = (arow & 7) << 4;
    const char* xtp = reinterpret_cast<const char*>(xt);

#pragma unroll
    for (int rt = 0; rt < 2; ++rt) {
        bfrag a[4];
#pragma unroll
        for (int kt = 0; kt < 4; ++kt)
            a[kt] = *reinterpret_cast<const bfrag*>(xtp + (((rt * 16 + arow) * 256 + kt * 64 + asub) ^ swz));
#pragma unroll
        for (int g = 0; g < 4; ++g) {
            f32x4 acc = {bg4[g], bg4[g], bg4[g], bg4[g]};
#pragma unroll
            for (int kt = 0; kt < 4; ++kt)
                acc = __builtin_amdgcn_mfma_f32_16x16x32_bf16(a[kt], wih[g][kt], acc, 0, 0, 0);
#pragma unroll
            for (int r = 0; r < 4; ++r)
                xp[(n0 + rt * 16 + hr0 + r) * 512 + g * 128 + colw] = b16(acc[r]);
        }
    }
}

// ====================== MAIN: LSTM loop with precomputed x-partials ======================
__global__ __launch_bounds__(512, 2)
void sage_xp(const float* __restrict__ feat, const int* __restrict__ nidx,
             const unsigned short* __restrict__ xp,
             const short* __restrict__ whhb, const short* __restrict__ w1b,
             const short* __restrict__ w2b, const float* __restrict__ biaso,
             float* __restrict__ out)
{
    __shared__ char lds[83968];      // P0 | P1 | h0 | h1
    __shared__ int  idx_s[MB * DEG];

    const int tid  = (int)threadIdx.x;
    const int lane = tid & 63;
    const int wave = tid >> 6;
    const int n0   = (int)blockIdx.x * MB;
    const int srow = tid >> 4;
    const int cs   = tid & 15;

    idx_s[tid]       = nidx[n0 * DEG + tid];
    idx_s[512 + tid] = nidx[n0 * DEG + 512 + tid];
    {   bfrag z = {0, 0, 0, 0, 0, 0, 0, 0};
        *reinterpret_cast<bfrag*>(lds + H0OFF + tid * 16) = z; }

    const int colw = wave * 16 + (lane & 15);
    bfrag whh[4][4];
#pragma unroll
    for (int g = 0; g < 4; ++g) {
        const short* phh = whhb + (g * 128 + colw) * FF + (lane >> 4) * 8;
#pragma unroll
        for (int kt = 0; kt < 4; ++kt)
            whh[g][kt] = *reinterpret_cast<const bfrag*>(phh + kt * 32);
    }
    __syncthreads();   // B1: idx_s + h0 zeros visible

    // ---- stage P for t=0 into P0 (each gload = one full XP row, 1 KB) ----
#pragma unroll
    for (int j = 0; j < 4; ++j) {
        int nd = idx_s[(wave * 4 + j) * DEG + 0];
        gload16(xp + nd * 512 + lane * 8, lds + P0OFF + (wave * 4 + j) * PPITCH);
    }
    __syncthreads();   // B2: P0 complete (compiler drains vmcnt before barrier)

    const int arow = lane & 15;
    const int asub = (lane >> 4) * 16;
    const int hr0  = (lane >> 4) * 4;
    const int swz  = (arow & 7) << 4;

    f32x4 cs0 = {0.f, 0.f, 0.f, 0.f};
    f32x4 cs1 = {0.f, 0.f, 0.f, 0.f};

    // read one gate's C-init (4 rows) from P tile
    auto rdP = [&](const char* pc, int goff) {
        f32x4 v;
        v[0] = bf2f(*reinterpret_cast<const unsigned short*>(pc + goff));
        v[1] = bf2f(*reinterpret_cast<const unsigned short*>(pc + goff + PPITCH));
        v[2] = bf2f(*reinterpret_cast<const unsigned short*>(pc + goff + 2 * PPITCH));
        v[3] = bf2f(*reinterpret_cast<const unsigned short*>(pc + goff + 3 * PPITCH));
        return v;
    };

    // one row-tile: gates = P + h@Whh^T, act, h-write
    auto dort = [&](int rt, int pcur, int hcur, int hnxt, f32x4& cst) {
        bfrag ha[4];
#pragma unroll
        for (int kt = 0; kt < 4; ++kt)
            ha[kt] = *reinterpret_cast<const bfrag*>(
                lds + hcur + (((rt * 16 + arow) * 256 + kt * 64 + asub) ^ swz));
        const char* pc = lds + pcur + (rt * 16 + hr0) * PPITCH + colw * 2;
        f32x4 gi = rdP(pc, 0), gf = rdP(pc, 256), gg = rdP(pc, 512), go = rdP(pc, 768);
#pragma unroll
        for (int kt = 0; kt < 4; ++kt) {
            gi = __builtin_amdgcn_mfma_f32_16x16x32_bf16(ha[kt], whh[0][kt], gi, 0, 0, 0);
            gf = __builtin_amdgcn_mfma_f32_16x16x32_bf16(ha[kt], whh[1][kt], gf, 0, 0, 0);
            gg = __builtin_amdgcn_mfma_f32_16x16x32_bf16(ha[kt], whh[2][kt], gg, 0, 0, 0);
            go = __builtin_amdgcn_mfma_f32_16x16x32_bf16(ha[kt], whh[3][kt], go, 0, 0, 0);
        }
#pragma unroll
        for (int r = 0; r < 4; ++r) {
            float av = __builtin_amdgcn_exp2f(-K1 * gi[r]);
            float bv = __builtin_amdgcn_exp2f(K2 * fminf(gg[r], 40.0f));
            float dv = __builtin_amdgcn_exp2f(-K1 * gf[r]);
            float ev = __builtin_amdgcn_exp2f(-K1 * go[r]);
            float t1 = __builtin_amdgcn_rcpf((1.0f + av) * (1.0f + bv));
            float t2 = __builtin_amdgcn_rcpf(1.0f + dv);
            float c  = fmaf(cst[r], t2, (bv - 1.0f) * t1);
            cst[r] = c;
            float uv = __builtin_amdgcn_exp2f(K2 * c);
            float t3 = __builtin_amdgcn_rcpf((1.0f + ev) * (1.0f + uv));
            float h  = (uv - 1.0f) * t3;
            int hrow = rt * 16 + hr0 + r;
            int hb   = (hrow * 256 + colw * 2) ^ ((hrow & 7) << 4);
            *reinterpret_cast<unsigned short*>(lds + hnxt + hb) = b16(h);
        }
    };

#define STEP(T, PCUR, PNXT, HCUR, HNXT)                                         \
    {                                                                           \
        if ((T) < DEG - 1) {                                                    \
            _Pragma("unroll")                                                   \
            for (int j = 0; j < 4; ++j) {                                       \
                int nd = idx_s[(wave * 4 + j) * DEG + (T) + 1];                 \
                gload16(xp + nd * 512 + lane * 8,                               \
                        lds + (PNXT) + (wave * 4 + j) * PPITCH);                \
            }                                                                   \
        }                                                                       \
        dort(0, PCUR, HCUR, HNXT, cs0);                                         \
        dort(1, PCUR, HCUR, HNXT, cs1);                                         \
        __syncthreads();                                                        \
    }

#pragma unroll 1
    for (int tt = 0; tt < DEG; tt += 2) {
        STEP(tt,     P0OFF, P1OFF, H0OFF, H1OFF);
        STEP(tt + 1, P1OFF, P0OFF, H1OFF, H0OFF);
    }
#undef STEP

    // ---- epilogue: out = feat@W1^T + (h/32)@W2^T + (b1+b2); h_final in h0 ----
    {   const float4* p = reinterpret_cast<const float4*>(feat + (n0 + srow) * FF + cs * 8);
        int sb = (srow * 256 + cs * 16) ^ ((srow & 7) << 4);
        *reinterpret_cast<bfrag*>(lds + P0OFF + sb) = pack8(p[0], p[1]); }
    __syncthreads();

    bfrag w1f[4], w2f[4];
#pragma unroll
    for (int kt = 0; kt < 4; ++kt) {
        w1f[kt] = *reinterpret_cast<const bfrag*>(w1b + colw * FF + kt * 32 + (lane >> 4) * 8);
        w2f[kt] = *reinterpret_cast<const bfrag*>(w2b + colw * FF + kt * 32 + (lane >> 4) * 8);
    }
    const float bb = biaso[colw];
#pragma unroll
    for (int rt = 0; rt < 2; ++rt) {
        bfrag fa[4], hfa[4];
#pragma unroll
        for (int kt = 0; kt < 4; ++kt) {
            int byte = ((rt * 16 + arow) * 256 + kt * 64 + asub) ^ swz;
            fa[kt]  = *reinterpret_cast<const bfrag*>(lds + P0OFF + byte);
            hfa[kt] = *reinterpret_cast<const bfrag*>(lds + H0OFF + byte);
        }
        f32x4 acc = {0.f, 0.f, 0.f, 0.f};
#pragma unroll
        for (int kt = 0; kt < 4; ++kt) {
            acc = __builtin_amdgcn_mfma_f32_16x16x32_bf16(fa[kt],  w1f[kt], acc, 0, 0, 0);
            acc = __builtin_amdgcn_mfma_f32_16x16x32_bf16(hfa[kt], w2f[kt], acc, 0, 0, 0);
        }
#pragma unroll
        for (int r = 0; r < 4; ++r) {
            int orow = n0 + rt * 16 + hr0 + r;
            out[orow * OO + colw] = acc[r] + bb;
        }
    }
}

// ====================== FALLBACK (R4/R9 structure, fp32 feat, in-loop x-MFMAs) ======================
__global__ __launch_bounds__(512, 2)
void sage_lstm_fb(const float* __restrict__ featf, const int* __restrict__ nidx,
                  const short* __restrict__ wihb, const short* __restrict__ whhb,
                  const short* __restrict__ w1b, const short* __restrict__ w2b,
                  const float* __restrict__ biasg, const float* __restrict__ biaso,
                  float* __restrict__ out)
{
    __shared__ short xbuf[2][MB * 128];
    __shared__ short hbuf[2][MB * 128];
    __shared__ int   idx_s[MB * DEG];

    const int tid  = (int)threadIdx.x;
    const int lane = tid & 63;
    const int wave = tid >> 6;
    const int n0   = (int)blockIdx.x * MB;
    const int srow = tid >> 4;
    const int cs   = tid & 15;

    idx_s[tid]       = nidx[n0 * DEG + tid];
    idx_s[512 + tid] = nidx[n0 * DEG + 512 + tid];
    {   bfrag z = {0, 0, 0, 0, 0, 0, 0, 0};
        reinterpret_cast<bfrag*>(hbuf[0])[tid] = z; }

    const int colw = wave * 16 + (lane & 15);
    bfrag wih[4][4], whh[4][4];
#pragma unroll
    for (int g = 0; g < 4; ++g) {
        const short* pih = wihb + (g * 128 + colw) * FF + (lane >> 4) * 8;
        const short* phh = whhb + (g * 128 + colw) * FF + (lane >> 4) * 8;
#pragma unroll
        for (int kt = 0; kt < 4; ++kt) {
            wih[g][kt] = *reinterpret_cast<const bfrag*>(pih + kt * 32);
            whh[g][kt] = *reinterpret_cast<const bfrag*>(phh + kt * 32);
        }
    }
    const float bi = biasg[colw];
    const float bf = biasg[128 + colw];
    const float bg = biasg[256 + colw];
    const float bo = biasg[384 + colw];
    const f32x4 bvi = {bi, bi, bi, bi};
    const f32x4 bvf = {bf, bf, bf, bf};
    const f32x4 bvg = {bg, bg, bg, bg};
    const f32x4 bvo = {bo, bo, bo, bo};

    __syncthreads();
    {
        const float4* p = reinterpret_cast<const float4*>(featf + idx_s[srow * DEG] * FF + cs * 8);
        int sb = (srow * 256 + cs * 16) ^ ((srow & 7) << 4);
        *reinterpret_cast<bfrag*>(reinterpret_cast<char*>(xbuf[0]) + sb) = pack8(p[0], p[1]);
    }
    __syncthreads();

    const int arow = lane & 15;
    const int asub = (lane >> 4) * 16;
    const int hr0  = (lane >> 4) * 4;
    const int swz  = (arow & 7) << 4;

    auto mm4 = [&](const char* p, int rbase, const bfrag (&W)[4][4],
                   f32x4& vi, f32x4& vf, f32x4& vg, f32x4& vo) {
        bfrag a[4];
#pragma unroll
        for (int kt = 0; kt < 4; ++kt)
            a[kt] = *reinterpret_cast<const bfrag*>(p + ((rbase * 256 + kt * 64 + asub) ^ swz));
#pragma unroll
        for (int kt = 0; kt < 4; ++kt) {
            vi = __builtin_amdgcn_mfma_f32_16x16x32_bf16(a[kt], W[0][kt], vi, 0, 0, 0);
            vf = __builtin_amdgcn_mfma_f32_16x16x32_bf16(a[kt], W[1][kt], vf, 0, 0, 0);
            vg = __builtin_amdgcn_mfma_f32_16x16x32_bf16(a[kt], W[2][kt], vg, 0, 0, 0);
            vo = __builtin_amdgcn_mfma_f32_16x16x32_bf16(a[kt], W[3][kt], vo, 0, 0, 0);
        }
    };
    auto actw = [&](f32x4& gi, f32x4& gf, f32x4& gg, f32x4& go,
                    f32x4& cst, char* hnxt, int rt) {
#pragma unroll
        for (int r = 0; r < 4; ++r) {
            float av = __builtin_amdgcn_exp2f(-K1 * gi[r]);
            float bv = __builtin_amdgcn_exp2f(K2 * fminf(gg[r], 40.0f));
            float dv = __builtin_amdgcn_exp2f(-K1 * gf[r]);
            float ev = __builtin_amdgcn_exp2f(-K1 * go[r]);
            float t1 = __builtin_amdgcn_rcpf((1.0f + av) * (1.0f + bv));
            float t2 = __builtin_amdgcn_rcpf(1.0f + dv);
            float c  = fmaf(cst[r], t2, (bv - 1.0f) * t1);
            cst[r] = c;
            float uv = __builtin_amdgcn_exp2f(K2 * c);
            float t3 = __builtin_amdgcn_rcpf((1.0f + ev) * (1.0f + uv));
            float h  = (uv - 1.0f) * t3;
            int hrow = rt * 16 + hr0 + r;
            int hb   = (hrow * 256 + colw * 2) ^ ((hrow & 7) << 4);
            *reinterpret_cast<unsigned short*>(hnxt + hb) = b16(h);
        }
    };

    f32x4 p0i, p0f, p0g, p0o, p1i, p1f, p1g, p1o;
    {
        char* x0p = reinterpret_cast<char*>(xbuf[0]);
        p0i = bvi; p0f = bvf; p0g = bvg; p0o = bvo;
        mm4(x0p, arow, wih, p0i, p0f, p0g, p0o);
        p1i = bvi; p1f = bvf; p1g = bvg; p1o = bvo;
        mm4(x0p, 16 + arow, wih, p1i, p1f, p1g, p1o);
    }
    {
        const float4* p = reinterpret_cast<const float4*>(featf + idx_s[srow * DEG + 1] * FF + cs * 8);
        int sb = (srow * 256 + cs * 16) ^ ((srow & 7) << 4);
        *reinterpret_cast<bfrag*>(reinterpret_cast<char*>(xbuf[1]) + sb) = pack8(p[0], p[1]);
    }
    __syncthreads();

    const f32x4 zz = {0.f, 0.f, 0.f, 0.f};
    f32x4 cs0 = zz, cs1 = zz;

#pragma unroll 2
    for (int t = 0; t < DEG; ++t) {
        const int cur = t & 1;
        char* hcur = reinterpret_cast<char*>(hbuf[cur]);
        char* hnxt = reinterpret_cast<char*>(hbuf[cur ^ 1]);
        char* xrd  = reinterpret_cast<char*>(xbuf[cur ^ 1]);
        char* xwr  = reinterpret_cast<char*>(xbuf[cur]);

        bfrag pre2;
        if (t < DEG - 2) {
            const float4* p = reinterpret_cast<const float4*>(featf + idx_s[srow * DEG + t + 2] * FF + cs * 8);
            pre2 = pack8(p[0], p[1]);
        }
        {
            f32x4 gi = p0i, gf = p0f, gg = p0g, go = p0o;
            mm4(hcur, arow, whh, gi, gf, gg, go);
            if (t < DEG - 1) {
                p0i = bvi; p0f = bvf; p0g = bvg; p0o = bvo;
                mm4(xrd, arow, wih, p0i, p0f, p0g, p0o);
            }
            actw(gi, gf, gg, go, cs0, hnxt, 0);
        }
        {
            f32x4 gi = p1i, gf = p1f, gg = p1g, go = p1o;
            mm4(hcur, 16 + arow, whh, gi, gf, gg, go);
            if (t < DEG - 1) {
                p1i = bvi; p1f = bvf; p1g = bvg; p1o = bvo;
                mm4(xrd, 16 + arow, wih, p1i, p1f, p1g, p1o);
            }
            actw(gi, gf, gg, go, cs1, hnxt, 1);
        }
        if (t < DEG - 2) {
            int sb = (srow * 256 + cs * 16) ^ ((srow & 7) << 4);
            *reinterpret_cast<bfrag*>(xwr + sb) = pre2;
        }
        __syncthreads();
    }

    {
        const float4* p = reinterpret_cast<const float4*>(featf + (n0 + srow) * FF + cs * 8);
        int sb = (srow * 256 + cs * 16) ^ ((srow & 7) << 4);
        *reinterpret_cast<bfrag*>(reinterpret_cast<char*>(xbuf[0]) + sb) = pack8(p[0], p[1]);
    }
    __syncthreads();

    char* const x0p = reinterpret_cast<char*>(xbuf[0]);
    char* const h0p = reinterpret_cast<char*>(hbuf[0]);
    bfrag w1f[4], w2f[4];
#pragma unroll
    for (int kt = 0; kt < 4; ++kt) {
        w1f[kt] = *reinterpret_cast<const bfrag*>(w1b + colw * FF + kt * 32 + (lane >> 4) * 8);
        w2f[kt] = *reinterpret_cast<const bfrag*>(w2b + colw * FF + kt * 32 + (lane >> 4) * 8);
    }
    const float bb = biaso[colw];
#pragma unroll
    for (int rt = 0; rt < 2; ++rt) {
        bfrag fa[4], hfa[4];
#pragma unroll
        for (int kt = 0; kt < 4; ++kt) {
            int byte = ((rt * 16 + arow) * 256 + kt * 64 + asub) ^ swz;
            fa[kt]  = *reinterpret_cast<const bfrag*>(x0p + byte);
            hfa[kt] = *reinterpret_cast<const bfrag*>(h0p + byte);
        }
        f32x4 acc = {0.f, 0.f, 0.f, 0.f};
#pragma unroll
        for (int kt = 0; kt < 4; ++kt) {
            acc = __builtin_amdgcn_mfma_f32_16x16x32_bf16(fa[kt],  w1f[kt], acc, 0, 0, 0);
            acc = __builtin_amdgcn_mfma_f32_16x16x32_bf16(hfa[kt], w2f[kt], acc, 0, 0, 0);
        }
#pragma unroll
        for (int r = 0; r < 4; ++r) {
            int orow = n0 + rt * 16 + hr0 + r;
            out[orow * OO + colw] = acc[r] + bb;
        }
    }
}

extern "C" void kernel_launch(void* const* d_in, const int* in_sizes, int n_in,
                              void* d_out, int out_size, void* d_ws, size_t ws_size,
                              hipStream_t stream)
{
    const float* feat = (const float*)d_in[0];
    const int*   nidx = (const int*)d_in[1];
    const float* W_ih = (const float*)d_in[2];
    const float* W_hh = (const float*)d_in[3];
    const float* b_ih = (const float*)d_in[4];
    const float* b_hh = (const float*)d_in[5];
    const float* W1   = (const float*)d_in[6];
    const float* b1   = (const float*)d_in[7];
    const float* W2   = (const float*)d_in[8];
    const float* b2   = (const float*)d_in[9];
    float* out = (float*)d_out;

    char* ws = (char*)d_ws;
    short* wihb  = (short*)(ws);             // 131072 B
    short* whhb  = (short*)(ws + 131072);    // 131072 B
    short* w1b   = (short*)(ws + 262144);    // 32768 B
    short* w2b   = (short*)(ws + 294912);    // 32768 B
    float* biasg = (float*)(ws + 327680);    // 2048 B
    float* biaso = (float*)(ws + 329728);    // 512 B
    unsigned short* xpb = (unsigned short*)(ws + 330240);   // 32768*512*2 = 33554432 B

    const size_t need = 330240 + (size_t)NN * 512 * 2;

    prep_weights<<<256, 256, 0, stream>>>(W_ih, W_hh, b_ih, b_hh, W1, b1, W2, b2,
                                          wihb, whhb, w1b, w2b, biasg, biaso);
    if (ws_size >= need) {
        xp_gemm<<<NN / MB, 512, 0, stream>>>(feat, wihb, biasg, xpb);
        sage_xp<<<NN / MB, 512, 0, stream>>>(feat, nidx, xpb, whhb, w1b, w2b, biaso, out);
    } else {
        sage_lstm_fb<<<NN / MB, 512, 0, stream>>>(feat, nidx, wihb, whhb,
                                                  w1b, w2b, biasg, biaso, out);
    }
}

// Round 11
// 307.494 us; speedup vs baseline: 1.3443x; 1.1689x over previous
//
#include <hip/hip_runtime.h>
#include <hip/hip_bf16.h>

#define NN 32768
#define DEG 32
#define FF 128
#define OO 128
#define MB 32    // nodes per block (prep/fallback kernels)
#define MB2 16   // nodes per block (main kernel)

#define K1 1.4426950408889634f
#define K2 2.8853900817779268f

// main-kernel LDS layout (bytes). PPITCH=1040: 16B-multiple (gload16 dest),
// and 4*PPITCH/4 % 32 == 16 -> rdP lane-groups split 2-way (free, m136).
#define PPITCH 1040
#define P0OFF 0
#define P1OFF 16640
#define H0OFF 33280
#define H1OFF 37376
#define LDSSZ 41472

typedef __attribute__((ext_vector_type(8))) short bfrag;
typedef __attribute__((ext_vector_type(4))) float f32x4;

__device__ __forceinline__ unsigned short b16(float x) {
    unsigned u = __float_as_uint(x) + 0x8000u;
    return (unsigned short)(u >> 16);
}
__device__ __forceinline__ float bf2f(unsigned short u) {
    return __uint_as_float((unsigned)u << 16);
}
__device__ __forceinline__ bfrag pack8(float4 a, float4 b) {
    bfrag r;
    r[0] = (short)b16(a.x); r[1] = (short)b16(a.y); r[2] = (short)b16(a.z); r[3] = (short)b16(a.w);
    r[4] = (short)b16(b.x); r[5] = (short)b16(b.y); r[6] = (short)b16(b.z); r[7] = (short)b16(b.w);
    return r;
}
__device__ __forceinline__ void gload16(const void* g, void* l) {
    __builtin_amdgcn_global_load_lds(
        (const __attribute__((address_space(1))) unsigned int*)g,
        (__attribute__((address_space(3))) unsigned int*)l, 16, 0, 0);
}

// -------- prep: weights/biases to bf16 (fold 1/deg into W2, combine biases) --------
__global__ void prep_weights(const float* __restrict__ wih, const float* __restrict__ whh,
                             const float* __restrict__ b_ih, const float* __restrict__ b_hh,
                             const float* __restrict__ w1, const float* __restrict__ b1,
                             const float* __restrict__ w2, const float* __restrict__ b2,
                             short* __restrict__ wihb, short* __restrict__ whhb,
                             short* __restrict__ w1b, short* __restrict__ w2b,
                             float* __restrict__ biasg, float* __restrict__ biaso)
{
    int i = blockIdx.x * blockDim.x + threadIdx.x;
    if (i < 512 * 128) { wihb[i] = (short)b16(wih[i]); whhb[i] = (short)b16(whh[i]); }
    if (i < 128 * 128) { w1b[i] = (short)b16(w1[i]); w2b[i] = (short)b16(w2[i] * 0.03125f); }
    if (i < 512) biasg[i] = b_ih[i] + b_hh[i];
    if (i < 128) biaso[i] = b1[i] + b2[i];
}

// -------- XP pre-GEMM: XP[n][g*128+c] = biasg[g*128+c] + feat[n]@W_ih[g*128+c]^T (bf16) --------
__global__ __launch_bounds__(512, 2)
void xp_gemm(const float* __restrict__ feat, const short* __restrict__ wihb,
             const float* __restrict__ biasg, unsigned short* __restrict__ xp)
{
    __shared__ short xt[MB * 128];

    const int tid  = (int)threadIdx.x;
    const int lane = tid & 63;
    const int wave = tid >> 6;
    const int n0   = (int)blockIdx.x * MB;
    const int srow = tid >> 4;
    const int cs   = tid & 15;

    {   const float4* p = reinterpret_cast<const float4*>(feat + (n0 + srow) * FF + cs * 8);
        int sb = (srow * 256 + cs * 16) ^ ((srow & 7) << 4);
        *reinterpret_cast<bfrag*>(reinterpret_cast<char*>(xt) + sb) = pack8(p[0], p[1]); }

    const int colw = wave * 16 + (lane & 15);
    bfrag wih[4][4];
#pragma unroll
    for (int g = 0; g < 4; ++g) {
        const short* pih = wihb + (g * 128 + colw) * FF + (lane >> 4) * 8;
#pragma unroll
        for (int kt = 0; kt < 4; ++kt)
            wih[g][kt] = *reinterpret_cast<const bfrag*>(pih + kt * 32);
    }
    float bg4[4];
#pragma unroll
    for (int g = 0; g < 4; ++g) bg4[g] = biasg[g * 128 + colw];

    __syncthreads();

    const int arow = lane & 15;
    const int asub = (lane >> 4) * 16;
    const int hr0  = (lane >> 4) * 4;
    const int swz  = (arow & 7) << 4;
    const char* xtp = reinterpret_cast<const char*>(xt);

#pragma unroll
    for (int rt = 0; rt < 2; ++rt) {
        bfrag a[4];
#pragma unroll
        for (int kt = 0; kt < 4; ++kt)
            a[kt] = *reinterpret_cast<const bfrag*>(xtp + (((rt * 16 + arow) * 256 + kt * 64 + asub) ^ swz));
#pragma unroll
        for (int g = 0; g < 4; ++g) {
            f32x4 acc = {bg4[g], bg4[g], bg4[g], bg4[g]};
#pragma unroll
            for (int kt = 0; kt < 4; ++kt)
                acc = __builtin_amdgcn_mfma_f32_16x16x32_bf16(a[kt], wih[g][kt], acc, 0, 0, 0);
#pragma unroll
            for (int r = 0; r < 4; ++r)
                xp[(n0 + rt * 16 + hr0 + r) * 512 + g * 128 + colw] = b16(acc[r]);
        }
    }
}

// ====================== MAIN: 256-thr blocks, 2 blocks/CU (TLP) ======================
// 16 nodes/block, 4 waves. Wave w owns hidden cols [32w, 32w+32) as 2 col-tiles.
// Two independent blocks co-resident per CU: one block's barrier/act phase is
// filled by the other block's MFMA/gather issue (m114 co-scheduling).
__global__ __launch_bounds__(256, 2)
void sage_xp2(const float* __restrict__ feat, const int* __restrict__ nidx,
              const unsigned short* __restrict__ xp,
              const short* __restrict__ whhb, const short* __restrict__ w1b,
              const short* __restrict__ w2b, const float* __restrict__ biaso,
              float* __restrict__ out)
{
    __shared__ char lds[LDSSZ];      // P0 | P1 | h0 | h1
    __shared__ int  idx_s[MB2 * DEG];

    const int tid  = (int)threadIdx.x;
    const int lane = tid & 63;
    const int wave = tid >> 6;                    // 0..3
    const int n0   = (int)blockIdx.x * MB2;
    const int srow = tid >> 4;                    // 0..15
    const int cs   = tid & 15;

    idx_s[tid]       = nidx[n0 * DEG + tid];
    idx_s[256 + tid] = nidx[n0 * DEG + 256 + tid];
    {   bfrag z = {0, 0, 0, 0, 0, 0, 0, 0};
        *reinterpret_cast<bfrag*>(lds + H0OFF + tid * 16) = z; }   // zero h0 (4 KB)

    // ---- Whh B-fragments for this wave's 2 col-tiles ----
    const int colb = wave * 32 + (lane & 15);     // ct=0 column; ct=1 is +16
    bfrag whh[2][4][4];
#pragma unroll
    for (int ct = 0; ct < 2; ++ct)
#pragma unroll
        for (int g = 0; g < 4; ++g) {
            const short* phh = whhb + (g * 128 + colb + ct * 16) * FF + (lane >> 4) * 8;
#pragma unroll
            for (int kt = 0; kt < 4; ++kt)
                whh[ct][g][kt] = *reinterpret_cast<const bfrag*>(phh + kt * 32);
        }
    __syncthreads();   // B1: idx_s + h0 zeros visible

    // ---- stage P(t=0) into P0: each wave stages 4 rows, 1 KB each ----
#pragma unroll
    for (int j = 0; j < 4; ++j) {
        int nd = idx_s[(wave * 4 + j) * DEG + 0];
        gload16(xp + nd * 512 + lane * 8, lds + P0OFF + (wave * 4 + j) * PPITCH);
    }
    __syncthreads();   // B2: P0 complete

    const int arow = lane & 15;
    const int asub = (lane >> 4) * 16;
    const int hr0  = (lane >> 4) * 4;
    const int swz  = (arow & 7) << 4;

    f32x4 cs0 = {0.f, 0.f, 0.f, 0.f};
    f32x4 cs1 = {0.f, 0.f, 0.f, 0.f};

    auto rdP = [&](const char* pc, int goff) {
        f32x4 v;
        v[0] = bf2f(*reinterpret_cast<const unsigned short*>(pc + goff));
        v[1] = bf2f(*reinterpret_cast<const unsigned short*>(pc + goff + PPITCH));
        v[2] = bf2f(*reinterpret_cast<const unsigned short*>(pc + goff + 2 * PPITCH));
        v[3] = bf2f(*reinterpret_cast<const unsigned short*>(pc + goff + 3 * PPITCH));
        return v;
    };

    // one col-tile: gates = P + h@Whh^T, act, h-write. ha shared across cts.
    auto doct = [&](int ct, const bfrag (&ha)[4], int pcur, int hnxt, f32x4& cst) {
        const int colw = colb + ct * 16;
        const char* pc = lds + pcur + hr0 * PPITCH + colw * 2;
        f32x4 gi = rdP(pc, 0), gf = rdP(pc, 256), gg = rdP(pc, 512), go = rdP(pc, 768);
#pragma unroll
        for (int kt = 0; kt < 4; ++kt) {
            gi = __builtin_amdgcn_mfma_f32_16x16x32_bf16(ha[kt], whh[ct][0][kt], gi, 0, 0, 0);
            gf = __builtin_amdgcn_mfma_f32_16x16x32_bf16(ha[kt], whh[ct][1][kt], gf, 0, 0, 0);
            gg = __builtin_amdgcn_mfma_f32_16x16x32_bf16(ha[kt], whh[ct][2][kt], gg, 0, 0, 0);
            go = __builtin_amdgcn_mfma_f32_16x16x32_bf16(ha[kt], whh[ct][3][kt], go, 0, 0, 0);
        }
#pragma unroll
        for (int r = 0; r < 4; ++r) {
            float av = __builtin_amdgcn_exp2f(-K1 * gi[r]);
            float bv = __builtin_amdgcn_exp2f(K2 * fminf(gg[r], 40.0f));
            float dv = __builtin_amdgcn_exp2f(-K1 * gf[r]);
            float ev = __builtin_amdgcn_exp2f(-K1 * go[r]);
            float t1 = __builtin_amdgcn_rcpf((1.0f + av) * (1.0f + bv));
            float t2 = __builtin_amdgcn_rcpf(1.0f + dv);
            float c  = fmaf(cst[r], t2, (bv - 1.0f) * t1);
            cst[r] = c;
            float uv = __builtin_amdgcn_exp2f(K2 * c);
            float t3 = __builtin_amdgcn_rcpf((1.0f + ev) * (1.0f + uv));
            float h  = (uv - 1.0f) * t3;
            int hrow = hr0 + r;
            int hb   = (hrow * 256 + colw * 2) ^ ((hrow & 7) << 4);
            *reinterpret_cast<unsigned short*>(lds + hnxt + hb) = b16(h);
        }
    };

#define STEP(T, PCUR, PNXT, HCUR, HNXT)                                         \
    {                                                                           \
        if ((T) < DEG - 1) {                                                    \
            _Pragma("unroll")                                                   \
            for (int j = 0; j < 4; ++j) {                                       \
                int nd = idx_s[(wave * 4 + j) * DEG + (T) + 1];                 \
                gload16(xp + nd * 512 + lane * 8,                               \
                        lds + (PNXT) + (wave * 4 + j) * PPITCH);                \
            }                                                                   \
        }                                                                       \
        bfrag ha[4];                                                            \
        _Pragma("unroll")                                                       \
        for (int kt = 0; kt < 4; ++kt)                                          \
            ha[kt] = *reinterpret_cast<const bfrag*>(                           \
                lds + (HCUR) + ((arow * 256 + kt * 64 + asub) ^ swz));          \
        doct(0, ha, PCUR, HNXT, cs0);                                           \
        doct(1, ha, PCUR, HNXT, cs1);                                           \
        __syncthreads();                                                        \
    }

#pragma unroll 1
    for (int tt = 0; tt < DEG; tt += 2) {
        STEP(tt,     P0OFF, P1OFF, H0OFF, H1OFF);
        STEP(tt + 1, P1OFF, P0OFF, H1OFF, H0OFF);
    }
#undef STEP

    // ---- epilogue: out = feat@W1^T + (h/32)@W2^T + (b1+b2); h_final in h0 ----
    {   const float4* p = reinterpret_cast<const float4*>(feat + (n0 + srow) * FF + cs * 8);
        int sb = (srow * 256 + cs * 16) ^ ((srow & 7) << 4);
        *reinterpret_cast<bfrag*>(lds + P0OFF + sb) = pack8(p[0], p[1]); }
    __syncthreads();

    bfrag w1f[2][4], w2f[2][4];
    float bb[2];
#pragma unroll
    for (int ct = 0; ct < 2; ++ct) {
        const int colw = colb + ct * 16;
#pragma unroll
        for (int kt = 0; kt < 4; ++kt) {
            w1f[ct][kt] = *reinterpret_cast<const bfrag*>(w1b + colw * FF + kt * 32 + (lane >> 4) * 8);
            w2f[ct][kt] = *reinterpret_cast<const bfrag*>(w2b + colw * FF + kt * 32 + (lane >> 4) * 8);
        }
        bb[ct] = biaso[colw];
    }
    bfrag fa[4], hfa[4];
#pragma unroll
    for (int kt = 0; kt < 4; ++kt) {
        int byte = (arow * 256 + kt * 64 + asub) ^ swz;
        fa[kt]  = *reinterpret_cast<const bfrag*>(lds + P0OFF + byte);
        hfa[kt] = *reinterpret_cast<const bfrag*>(lds + H0OFF + byte);
    }
#pragma unroll
    for (int ct = 0; ct < 2; ++ct) {
        f32x4 acc = {0.f, 0.f, 0.f, 0.f};
#pragma unroll
        for (int kt = 0; kt < 4; ++kt) {
            acc = __builtin_amdgcn_mfma_f32_16x16x32_bf16(fa[kt],  w1f[ct][kt], acc, 0, 0, 0);
            acc = __builtin_amdgcn_mfma_f32_16x16x32_bf16(hfa[kt], w2f[ct][kt], acc, 0, 0, 0);
        }
#pragma unroll
        for (int r = 0; r < 4; ++r) {
            int orow = n0 + hr0 + r;
            out[orow * OO + colb + ct * 16] = acc[r] + bb[ct];
        }
    }
}

// ====================== FALLBACK (R4 structure, fp32 feat, in-loop x-MFMAs) ======================
__global__ __launch_bounds__(512, 2)
void sage_lstm_fb(const float* __restrict__ featf, const int* __restrict__ nidx,
                  const short* __restrict__ wihb, const short* __restrict__ whhb,
                  const short* __restrict__ w1b, const short* __restrict__ w2b,
                  const float* __restrict__ biasg, const float* __restrict__ biaso,
                  float* __restrict__ out)
{
    __shared__ short xbuf[2][MB * 128];
    __shared__ short hbuf[2][MB * 128];
    __shared__ int   idx_s[MB * DEG];

    const int tid  = (int)threadIdx.x;
    const int lane = tid & 63;
    const int wave = tid >> 6;
    const int n0   = (int)blockIdx.x * MB;
    const int srow = tid >> 4;
    const int cs   = tid & 15;

    idx_s[tid]       = nidx[n0 * DEG + tid];
    idx_s[512 + tid] = nidx[n0 * DEG + 512 + tid];
    {   bfrag z = {0, 0, 0, 0, 0, 0, 0, 0};
        reinterpret_cast<bfrag*>(hbuf[0])[tid] = z; }

    const int colw = wave * 16 + (lane & 15);
    bfrag wih[4][4], whh[4][4];
#pragma unroll
    for (int g = 0; g < 4; ++g) {
        const short* pih = wihb + (g * 128 + colw) * FF + (lane >> 4) * 8;
        const short* phh = whhb + (g * 128 + colw) * FF + (lane >> 4) * 8;
#pragma unroll
        for (int kt = 0; kt < 4; ++kt) {
            wih[g][kt] = *reinterpret_cast<const bfrag*>(pih + kt * 32);
            whh[g][kt] = *reinterpret_cast<const bfrag*>(phh + kt * 32);
        }
    }
    const float bi = biasg[colw];
    const float bf = biasg[128 + colw];
    const float bg = biasg[256 + colw];
    const float bo = biasg[384 + colw];
    const f32x4 bvi = {bi, bi, bi, bi};
    const f32x4 bvf = {bf, bf, bf, bf};
    const f32x4 bvg = {bg, bg, bg, bg};
    const f32x4 bvo = {bo, bo, bo, bo};

    __syncthreads();
    {
        const float4* p = reinterpret_cast<const float4*>(featf + idx_s[srow * DEG] * FF + cs * 8);
        int sb = (srow * 256 + cs * 16) ^ ((srow & 7) << 4);
        *reinterpret_cast<bfrag*>(reinterpret_cast<char*>(xbuf[0]) + sb) = pack8(p[0], p[1]);
    }
    __syncthreads();

    const int arow = lane & 15;
    const int asub = (lane >> 4) * 16;
    const int hr0  = (lane >> 4) * 4;
    const int swz  = (arow & 7) << 4;

    auto mm4 = [&](const char* p, int rbase, const bfrag (&W)[4][4],
                   f32x4& vi, f32x4& vf, f32x4& vg, f32x4& vo) {
        bfrag a[4];
#pragma unroll
        for (int kt = 0; kt < 4; ++kt)
            a[kt] = *reinterpret_cast<const bfrag*>(p + ((rbase * 256 + kt * 64 + asub) ^ swz));
#pragma unroll
        for (int kt = 0; kt < 4; ++kt) {
            vi = __builtin_amdgcn_mfma_f32_16x16x32_bf16(a[kt], W[0][kt], vi, 0, 0, 0);
            vf = __builtin_amdgcn_mfma_f32_16x16x32_bf16(a[kt], W[1][kt], vf, 0, 0, 0);
            vg = __builtin_amdgcn_mfma_f32_16x16x32_bf16(a[kt], W[2][kt], vg, 0, 0, 0);
            vo = __builtin_amdgcn_mfma_f32_16x16x32_bf16(a[kt], W[3][kt], vo, 0, 0, 0);
        }
    };
    auto actw = [&](f32x4& gi, f32x4& gf, f32x4& gg, f32x4& go,
                    f32x4& cst, char* hnxt, int rt) {
#pragma unroll
        for (int r = 0; r < 4; ++r) {
            float av = __builtin_amdgcn_exp2f(-K1 * gi[r]);
            float bv = __builtin_amdgcn_exp2f(K2 * fminf(gg[r], 40.0f));
            float dv = __builtin_amdgcn_exp2f(-K1 * gf[r]);
            float ev = __builtin_amdgcn_exp2f(-K1 * go[r]);
            float t1 = __builtin_amdgcn_rcpf((1.0f + av) * (1.0f + bv));
            float t2 = __builtin_amdgcn_rcpf(1.0f + dv);
            float c  = fmaf(cst[r], t2, (bv - 1.0f) * t1);
            cst[r] = c;
            float uv = __builtin_amdgcn_exp2f(K2 * c);
            float t3 = __builtin_amdgcn_rcpf((1.0f + ev) * (1.0f + uv));
            float h  = (uv - 1.0f) * t3;
            int hrow = rt * 16 + hr0 + r;
            int hb   = (hrow * 256 + colw * 2) ^ ((hrow & 7) << 4);
            *reinterpret_cast<unsigned short*>(hnxt + hb) = b16(h);
        }
    };

    f32x4 p0i, p0f, p0g, p0o, p1i, p1f, p1g, p1o;
    {
        char* x0p = reinterpret_cast<char*>(xbuf[0]);
        p0i = bvi; p0f = bvf; p0g = bvg; p0o = bvo;
        mm4(x0p, arow, wih, p0i, p0f, p0g, p0o);
        p1i = bvi; p1f = bvf; p1g = bvg; p1o = bvo;
        mm4(x0p, 16 + arow, wih, p1i, p1f, p1g, p1o);
    }
    {
        const float4* p = reinterpret_cast<const float4*>(featf + idx_s[srow * DEG + 1] * FF + cs * 8);
        int sb = (srow * 256 + cs * 16) ^ ((srow & 7) << 4);
        *reinterpret_cast<bfrag*>(reinterpret_cast<char*>(xbuf[1]) + sb) = pack8(p[0], p[1]);
    }
    __syncthreads();

    const f32x4 zz = {0.f, 0.f, 0.f, 0.f};
    f32x4 cs0 = zz, cs1 = zz;

#pragma unroll 2
    for (int t = 0; t < DEG; ++t) {
        const int cur = t & 1;
        char* hcur = reinterpret_cast<char*>(hbuf[cur]);
        char* hnxt = reinterpret_cast<char*>(hbuf[cur ^ 1]);
        char* xrd  = reinterpret_cast<char*>(xbuf[cur ^ 1]);
        char* xwr  = reinterpret_cast<char*>(xbuf[cur]);

        bfrag pre2;
        if (t < DEG - 2) {
            const float4* p = reinterpret_cast<const float4*>(featf + idx_s[srow * DEG + t + 2] * FF + cs * 8);
            pre2 = pack8(p[0], p[1]);
        }
        {
            f32x4 gi = p0i, gf = p0f, gg = p0g, go = p0o;
            mm4(hcur, arow, whh, gi, gf, gg, go);
            if (t < DEG - 1) {
                p0i = bvi; p0f = bvf; p0g = bvg; p0o = bvo;
                mm4(xrd, arow, wih, p0i, p0f, p0g, p0o);
            }
            actw(gi, gf, gg, go, cs0, hnxt, 0);
        }
        {
            f32x4 gi = p1i, gf = p1f, gg = p1g, go = p1o;
            mm4(hcur, 16 + arow, whh, gi, gf, gg, go);
            if (t < DEG - 1) {
                p1i = bvi; p1f = bvf; p1g = bvg; p1o = bvo;
                mm4(xrd, 16 + arow, wih, p1i, p1f, p1g, p1o);
            }
            actw(gi, gf, gg, go, cs1, hnxt, 1);
        }
        if (t < DEG - 2) {
            int sb = (srow * 256 + cs * 16) ^ ((srow & 7) << 4);
            *reinterpret_cast<bfrag*>(xwr + sb) = pre2;
        }
        __syncthreads();
    }

    {
        const float4* p = reinterpret_cast<const float4*>(featf + (n0 + srow) * FF + cs * 8);
        int sb = (srow * 256 + cs * 16) ^ ((srow & 7) << 4);
        *reinterpret_cast<bfrag*>(reinterpret_cast<char*>(xbuf[0]) + sb) = pack8(p[0], p[1]);
    }
    __syncthreads();

    char* const x0p = reinterpret_cast<char*>(xbuf[0]);
    char* const h0p = reinterpret_cast<char*>(hbuf[0]);
    bfrag w1f[4], w2f[4];
#pragma unroll
    for (int kt = 0; kt < 4; ++kt) {
        w1f[kt] = *reinterpret_cast<const bfrag*>(w1b + colw * FF + kt * 32 + (lane >> 4) * 8);
        w2f[kt] = *reinterpret_cast<const bfrag*>(w2b + colw * FF + kt * 32 + (lane >> 4) * 8);
    }
    const float bb = biaso[colw];
#pragma unroll
    for (int rt = 0; rt < 2; ++rt) {
        bfrag fa[4], hfa[4];
#pragma unroll
        for (int kt = 0; kt < 4; ++kt) {
            int byte = ((rt * 16 + arow) * 256 + kt * 64 + asub) ^ swz;
            fa[kt]  = *reinterpret_cast<const bfrag*>(x0p + byte);
            hfa[kt] = *reinterpret_cast<const bfrag*>(h0p + byte);
        }
        f32x4 acc = {0.f, 0.f, 0.f, 0.f};
#pragma unroll
        for (int kt = 0; kt < 4; ++kt) {
            acc = __builtin_amdgcn_mfma_f32_16x16x32_bf16(fa[kt],  w1f[kt], acc, 0, 0, 0);
            acc = __builtin_amdgcn_mfma_f32_16x16x32_bf16(hfa[kt], w2f[kt], acc, 0, 0, 0);
        }
#pragma unroll
        for (int r = 0; r < 4; ++r) {
            int orow = n0 + rt * 16 + hr0 + r;
            out[orow * OO + colw] = acc[r] + bb;
        }
    }
}

extern "C" void kernel_launch(void* const* d_in, const int* in_sizes, int n_in,
                              void* d_out, int out_size, void* d_ws, size_t ws_size,
                              hipStream_t stream)
{
    const float* feat = (const float*)d_in[0];
    const int*   nidx = (const int*)d_in[1];
    const float* W_ih = (const float*)d_in[2];
    const float* W_hh = (const float*)d_in[3];
    const float* b_ih = (const float*)d_in[4];
    const float* b_hh = (const float*)d_in[5];
    const float* W1   = (const float*)d_in[6];
    const float* b1   = (const float*)d_in[7];
    const float* W2   = (const float*)d_in[8];
    const float* b2   = (const float*)d_in[9];
    float* out = (float*)d_out;

    char* ws = (char*)d_ws;
    short* wihb  = (short*)(ws);             // 131072 B
    short* whhb  = (short*)(ws + 131072);    // 131072 B
    short* w1b   = (short*)(ws + 262144);    // 32768 B
    short* w2b   = (short*)(ws + 294912);    // 32768 B
    float* biasg = (float*)(ws + 327680);    // 2048 B
    float* biaso = (float*)(ws + 329728);    // 512 B
    unsigned short* xpb = (unsigned short*)(ws + 330240);   // 33554432 B

    const size_t need = 330240 + (size_t)NN * 512 * 2;

    prep_weights<<<256, 256, 0, stream>>>(W_ih, W_hh, b_ih, b_hh, W1, b1, W2, b2,
                                          wihb, whhb, w1b, w2b, biasg, biaso);
    if (ws_size >= need) {
        xp_gemm<<<NN / MB, 512, 0, stream>>>(feat, wihb, biasg, xpb);
        sage_xp2<<<NN / MB2, 256, 0, stream>>>(feat, nidx, xpb, whhb, w1b, w2b, biaso, out);
    } else {
        sage_lstm_fb<<<NN / MB, 512, 0, stream>>>(feat, nidx, wihb, whhb,
                                                  w1b, w2b, biasg, biaso, out);
    }
}

// Round 12
// 299.978 us; speedup vs baseline: 1.3780x; 1.0251x over previous
//
#include <hip/hip_runtime.h>
#include <hip/hip_bf16.h>

#define NN 32768
#define DEG 32
#define FF 128
#define OO 128
#define MB 32    // nodes per block (prep/fallback kernels)
#define MB2 16   // nodes per block (main kernel)

#define K1 1.4426950408889634f
#define K2 2.8853900817779268f

// main-kernel LDS layout (bytes): 3 P buffers (distance-2 pipeline) + h ping-pong
#define PPITCH 1040          // 512 u16 + 8 pad u16; 16B-multiple (gload16 dest)
#define P0OFF 0
#define P1OFF 16640
#define P2OFF 33280
#define H0OFF 49920
#define H1OFF 54016
#define LDSSZ 58112

typedef __attribute__((ext_vector_type(8))) short bfrag;
typedef __attribute__((ext_vector_type(4))) float f32x4;

__device__ __forceinline__ unsigned short b16(float x) {
    unsigned u = __float_as_uint(x) + 0x8000u;
    return (unsigned short)(u >> 16);
}
__device__ __forceinline__ float bf2f(unsigned short u) {
    return __uint_as_float((unsigned)u << 16);
}
__device__ __forceinline__ bfrag pack8(float4 a, float4 b) {
    bfrag r;
    r[0] = (short)b16(a.x); r[1] = (short)b16(a.y); r[2] = (short)b16(a.z); r[3] = (short)b16(a.w);
    r[4] = (short)b16(b.x); r[5] = (short)b16(b.y); r[6] = (short)b16(b.z); r[7] = (short)b16(b.w);
    return r;
}
__device__ __forceinline__ void gload16(const void* g, void* l) {
    __builtin_amdgcn_global_load_lds(
        (const __attribute__((address_space(1))) unsigned int*)g,
        (__attribute__((address_space(3))) unsigned int*)l, 16, 0, 0);
}

// -------- prep: weights/biases to bf16 (fold 1/deg into W2, combine biases) --------
__global__ void prep_weights(const float* __restrict__ wih, const float* __restrict__ whh,
                             const float* __restrict__ b_ih, const float* __restrict__ b_hh,
                             const float* __restrict__ w1, const float* __restrict__ b1,
                             const float* __restrict__ w2, const float* __restrict__ b2,
                             short* __restrict__ wihb, short* __restrict__ whhb,
                             short* __restrict__ w1b, short* __restrict__ w2b,
                             float* __restrict__ biasg, float* __restrict__ biaso)
{
    int i = blockIdx.x * blockDim.x + threadIdx.x;
    if (i < 512 * 128) { wihb[i] = (short)b16(wih[i]); whhb[i] = (short)b16(whh[i]); }
    if (i < 128 * 128) { w1b[i] = (short)b16(w1[i]); w2b[i] = (short)b16(w2[i] * 0.03125f); }
    if (i < 512) biasg[i] = b_ih[i] + b_hh[i];
    if (i < 128) biaso[i] = b1[i] + b2[i];
}

// -------- XP pre-GEMM, gate-interleaved layout: XP[n][col*4 + g] (bf16) --------
__global__ __launch_bounds__(512, 2)
void xp_gemm(const float* __restrict__ feat, const short* __restrict__ wihb,
             const float* __restrict__ biasg, unsigned short* __restrict__ xp)
{
    __shared__ short xt[MB * 128];

    const int tid  = (int)threadIdx.x;
    const int lane = tid & 63;
    const int wave = tid >> 6;
    const int n0   = (int)blockIdx.x * MB;
    const int srow = tid >> 4;
    const int cs   = tid & 15;

    {   const float4* p = reinterpret_cast<const float4*>(feat + (n0 + srow) * FF + cs * 8);
        int sb = (srow * 256 + cs * 16) ^ ((srow & 7) << 4);
        *reinterpret_cast<bfrag*>(reinterpret_cast<char*>(xt) + sb) = pack8(p[0], p[1]); }

    const int colw = wave * 16 + (lane & 15);
    bfrag wih[4][4];
#pragma unroll
    for (int g = 0; g < 4; ++g) {
        const short* pih = wihb + (g * 128 + colw) * FF + (lane >> 4) * 8;
#pragma unroll
        for (int kt = 0; kt < 4; ++kt)
            wih[g][kt] = *reinterpret_cast<const bfrag*>(pih + kt * 32);
    }
    float bg4[4];
#pragma unroll
    for (int g = 0; g < 4; ++g) bg4[g] = biasg[g * 128 + colw];

    __syncthreads();

    const int arow = lane & 15;
    const int asub = (lane >> 4) * 16;
    const int hr0  = (lane >> 4) * 4;
    const int swz  = (arow & 7) << 4;
    const char* xtp = reinterpret_cast<const char*>(xt);

#pragma unroll
    for (int rt = 0; rt < 2; ++rt) {
        bfrag a[4];
#pragma unroll
        for (int kt = 0; kt < 4; ++kt)
            a[kt] = *reinterpret_cast<const bfrag*>(xtp + (((rt * 16 + arow) * 256 + kt * 64 + asub) ^ swz));
        f32x4 acc0 = {bg4[0], bg4[0], bg4[0], bg4[0]};
        f32x4 acc1 = {bg4[1], bg4[1], bg4[1], bg4[1]};
        f32x4 acc2 = {bg4[2], bg4[2], bg4[2], bg4[2]};
        f32x4 acc3 = {bg4[3], bg4[3], bg4[3], bg4[3]};
#pragma unroll
        for (int kt = 0; kt < 4; ++kt) {
            acc0 = __builtin_amdgcn_mfma_f32_16x16x32_bf16(a[kt], wih[0][kt], acc0, 0, 0, 0);
            acc1 = __builtin_amdgcn_mfma_f32_16x16x32_bf16(a[kt], wih[1][kt], acc1, 0, 0, 0);
            acc2 = __builtin_amdgcn_mfma_f32_16x16x32_bf16(a[kt], wih[2][kt], acc2, 0, 0, 0);
            acc3 = __builtin_amdgcn_mfma_f32_16x16x32_bf16(a[kt], wih[3][kt], acc3, 0, 0, 0);
        }
#pragma unroll
        for (int r = 0; r < 4; ++r) {
            ushort4 pk;
            pk.x = b16(acc0[r]); pk.y = b16(acc1[r]);
            pk.z = b16(acc2[r]); pk.w = b16(acc3[r]);
            *reinterpret_cast<ushort4*>(xp + (size_t)(n0 + rt * 16 + hr0 + r) * 512 + colw * 4) = pk;
        }
    }
}

// ====================== MAIN: 2 blocks/CU + distance-2 counted-vmcnt pipeline ======================
// 16 nodes/block, 4 waves; wave owns 2 col-tiles (whh in 128 regs).
// Per step: issue P(t+2) gathers; compute gates(t) = P(t) + h@Whh; act; h-write;
// end with lgkmcnt(0) + vmcnt(4) + raw s_barrier -> the 4 freshly-issued loads
// stay in flight across the barrier (T4: never drain vmcnt to 0 in the loop).
__global__ __launch_bounds__(256, 2)
void sage_xp3(const float* __restrict__ feat, const int* __restrict__ nidx,
              const unsigned short* __restrict__ xp,
              const short* __restrict__ whhb, const short* __restrict__ w1b,
              const short* __restrict__ w2b, const float* __restrict__ biaso,
              float* __restrict__ out)
{
    __shared__ char lds[LDSSZ];      // P0 | P1 | P2 | h0 | h1
    __shared__ int  idx_s[MB2 * DEG];

    const int tid  = (int)threadIdx.x;
    const int lane = tid & 63;
    const int wave = tid >> 6;                    // 0..3
    const int n0   = (int)blockIdx.x * MB2;
    const int srow = tid >> 4;                    // 0..15
    const int cs   = tid & 15;

    idx_s[tid]       = nidx[n0 * DEG + tid];
    idx_s[256 + tid] = nidx[n0 * DEG + 256 + tid];
    {   bfrag z = {0, 0, 0, 0, 0, 0, 0, 0};
        *reinterpret_cast<bfrag*>(lds + H0OFF + tid * 16) = z; }   // zero h0 (4 KB)

    const int colb = wave * 32 + (lane & 15);     // ct=0 column; ct=1 is +16
    bfrag whh[2][4][4];
#pragma unroll
    for (int ct = 0; ct < 2; ++ct)
#pragma unroll
        for (int g = 0; g < 4; ++g) {
            const short* phh = whhb + (g * 128 + colb + ct * 16) * FF + (lane >> 4) * 8;
#pragma unroll
            for (int kt = 0; kt < 4; ++kt)
                whh[ct][g][kt] = *reinterpret_cast<const bfrag*>(phh + kt * 32);
        }
    __syncthreads();   // B1: idx_s + h0 zeros visible

    // ---- prologue: stage P(0)->P0 and P(1)->P1; wait own P0 loads; barrier ----
#pragma unroll
    for (int j = 0; j < 4; ++j) {
        int nd0 = idx_s[(wave * 4 + j) * DEG + 0];
        gload16(xp + (size_t)nd0 * 512 + lane * 8, lds + P0OFF + (wave * 4 + j) * PPITCH);
    }
#pragma unroll
    for (int j = 0; j < 4; ++j) {
        int nd1 = idx_s[(wave * 4 + j) * DEG + 1];
        gload16(xp + (size_t)nd1 * 512 + lane * 8, lds + P1OFF + (wave * 4 + j) * PPITCH);
    }
    asm volatile("s_waitcnt vmcnt(4)" ::: "memory");
    __builtin_amdgcn_sched_barrier(0);
    __builtin_amdgcn_s_barrier();
    __builtin_amdgcn_sched_barrier(0);

    const int arow = lane & 15;
    const int asub = (lane >> 4) * 16;
    const int hr0  = (lane >> 4) * 4;
    const int swz  = (arow & 7) << 4;

    f32x4 cs0 = {0.f, 0.f, 0.f, 0.f};
    f32x4 cs1 = {0.f, 0.f, 0.f, 0.f};

    // one col-tile: gates = P(packed b64 reads) + h@Whh^T, act, h-write
    auto doct = [&](int ct, const bfrag (&ha)[4], int pcur, int hnxt, f32x4& cst) {
        const int colw = colb + ct * 16;
        const char* pc = lds + pcur + hr0 * PPITCH + colw * 8;
        f32x4 gi, gf, gg, go;
#pragma unroll
        for (int r = 0; r < 4; ++r) {
            ushort4 pv = *reinterpret_cast<const ushort4*>(pc + r * PPITCH);
            gi[r] = bf2f(pv.x); gf[r] = bf2f(pv.y); gg[r] = bf2f(pv.z); go[r] = bf2f(pv.w);
        }
#pragma unroll
        for (int kt = 0; kt < 4; ++kt) {
            gi = __builtin_amdgcn_mfma_f32_16x16x32_bf16(ha[kt], whh[ct][0][kt], gi, 0, 0, 0);
            gf = __builtin_amdgcn_mfma_f32_16x16x32_bf16(ha[kt], whh[ct][1][kt], gf, 0, 0, 0);
            gg = __builtin_amdgcn_mfma_f32_16x16x32_bf16(ha[kt], whh[ct][2][kt], gg, 0, 0, 0);
            go = __builtin_amdgcn_mfma_f32_16x16x32_bf16(ha[kt], whh[ct][3][kt], go, 0, 0, 0);
        }
#pragma unroll
        for (int r = 0; r < 4; ++r) {
            float av = __builtin_amdgcn_exp2f(-K1 * gi[r]);
            float bv = __builtin_amdgcn_exp2f(K2 * fminf(gg[r], 40.0f));
            float dv = __builtin_amdgcn_exp2f(-K1 * gf[r]);
            float ev = __builtin_amdgcn_exp2f(-K1 * go[r]);
            float t1 = __builtin_amdgcn_rcpf((1.0f + av) * (1.0f + bv));
            float t2 = __builtin_amdgcn_rcpf(1.0f + dv);
            float c  = fmaf(cst[r], t2, (bv - 1.0f) * t1);
            cst[r] = c;
            float uv = __builtin_amdgcn_exp2f(K2 * c);
            float t3 = __builtin_amdgcn_rcpf((1.0f + ev) * (1.0f + uv));
            float h  = (uv - 1.0f) * t3;
            int hrow = hr0 + r;
            int hb   = (hrow * 256 + colw * 2) ^ ((hrow & 7) << 4);
            *reinterpret_cast<unsigned short*>(lds + hnxt + hb) = b16(h);
        }
    };

// counted step: issue P(T+2), compute T, counted-wait + raw barrier
#define STEPC(T, PCUR, PNXT, HCUR, HNXT)                                        \
    {                                                                           \
        _Pragma("unroll")                                                       \
        for (int j = 0; j < 4; ++j) {                                           \
            int nd = idx_s[(wave * 4 + j) * DEG + (T) + 2];                     \
            gload16(xp + (size_t)nd * 512 + lane * 8,                           \
                    lds + (PNXT) + (wave * 4 + j) * PPITCH);                    \
        }                                                                       \
        bfrag ha[4];                                                            \
        _Pragma("unroll")                                                       \
        for (int kt = 0; kt < 4; ++kt)                                          \
            ha[kt] = *reinterpret_cast<const bfrag*>(                           \
                lds + (HCUR) + ((arow * 256 + kt * 64 + asub) ^ swz));          \
        doct(0, ha, PCUR, HNXT, cs0);                                           \
        doct(1, ha, PCUR, HNXT, cs1);                                           \
        asm volatile("s_waitcnt lgkmcnt(0)" ::: "memory");                      \
        asm volatile("s_waitcnt vmcnt(4)" ::: "memory");                        \
        __builtin_amdgcn_sched_barrier(0);                                      \
        __builtin_amdgcn_s_barrier();                                           \
        __builtin_amdgcn_sched_barrier(0);                                      \
    }

// final steps: no issue; full drain via __syncthreads
#define STEPF(T, PCUR, HCUR, HNXT)                                              \
    {                                                                           \
        bfrag ha[4];                                                            \
        _Pragma("unroll")                                                       \
        for (int kt = 0; kt < 4; ++kt)                                          \
            ha[kt] = *reinterpret_cast<const bfrag*>(                           \
                lds + (HCUR) + ((arow * 256 + kt * 64 + asub) ^ swz));          \
        doct(0, ha, PCUR, HNXT, cs0);                                           \
        doct(1, ha, PCUR, HNXT, cs1);                                           \
        __syncthreads();                                                        \
    }

#pragma unroll 1
    for (int b6 = 0; b6 < 30; b6 += 6) {
        STEPC(b6 + 0, P0OFF, P2OFF, H0OFF, H1OFF);
        STEPC(b6 + 1, P1OFF, P0OFF, H1OFF, H0OFF);
        STEPC(b6 + 2, P2OFF, P1OFF, H0OFF, H1OFF);
        STEPC(b6 + 3, P0OFF, P2OFF, H1OFF, H0OFF);
        STEPC(b6 + 4, P1OFF, P0OFF, H0OFF, H1OFF);
        STEPC(b6 + 5, P2OFF, P1OFF, H1OFF, H0OFF);
    }
    STEPF(30, P0OFF, H0OFF, H1OFF);
    STEPF(31, P1OFF, H1OFF, H0OFF);
#undef STEPC
#undef STEPF

    // ---- epilogue: out = feat@W1^T + (h/32)@W2^T + (b1+b2); h_final in h0 ----
    {   const float4* p = reinterpret_cast<const float4*>(feat + (n0 + srow) * FF + cs * 8);
        int sb = (srow * 256 + cs * 16) ^ ((srow & 7) << 4);
        *reinterpret_cast<bfrag*>(lds + P0OFF + sb) = pack8(p[0], p[1]); }
    __syncthreads();

    bfrag w1f[2][4], w2f[2][4];
    float bb[2];
#pragma unroll
    for (int ct = 0; ct < 2; ++ct) {
        const int colw = colb + ct * 16;
#pragma unroll
        for (int kt = 0; kt < 4; ++kt) {
            w1f[ct][kt] = *reinterpret_cast<const bfrag*>(w1b + colw * FF + kt * 32 + (lane >> 4) * 8);
            w2f[ct][kt] = *reinterpret_cast<const bfrag*>(w2b + colw * FF + kt * 32 + (lane >> 4) * 8);
        }
        bb[ct] = biaso[colw];
    }
    bfrag fa[4], hfa[4];
#pragma unroll
    for (int kt = 0; kt < 4; ++kt) {
        int byte = (arow * 256 + kt * 64 + asub) ^ swz;
        fa[kt]  = *reinterpret_cast<const bfrag*>(lds + P0OFF + byte);
        hfa[kt] = *reinterpret_cast<const bfrag*>(lds + H0OFF + byte);
    }
#pragma unroll
    for (int ct = 0; ct < 2; ++ct) {
        f32x4 acc = {0.f, 0.f, 0.f, 0.f};
#pragma unroll
        for (int kt = 0; kt < 4; ++kt) {
            acc = __builtin_amdgcn_mfma_f32_16x16x32_bf16(fa[kt],  w1f[ct][kt], acc, 0, 0, 0);
            acc = __builtin_amdgcn_mfma_f32_16x16x32_bf16(hfa[kt], w2f[ct][kt], acc, 0, 0, 0);
        }
#pragma unroll
        for (int r = 0; r < 4; ++r) {
            int orow = n0 + hr0 + r;
            out[orow * OO + colb + ct * 16] = acc[r] + bb[ct];
        }
    }
}

// ====================== FALLBACK (R4 structure, fp32 feat, in-loop x-MFMAs) ======================
__global__ __launch_bounds__(512, 2)
void sage_lstm_fb(const float* __restrict__ featf, const int* __restrict__ nidx,
                  const short* __restrict__ wihb, const short* __restrict__ whhb,
                  const short* __restrict__ w1b, const short* __restrict__ w2b,
                  const float* __restrict__ biasg, const float* __restrict__ biaso,
                  float* __restrict__ out)
{
    __shared__ short xbuf[2][MB * 128];
    __shared__ short hbuf[2][MB * 128];
    __shared__ int   idx_s[MB * DEG];

    const int tid  = (int)threadIdx.x;
    const int lane = tid & 63;
    const int wave = tid >> 6;
    const int n0   = (int)blockIdx.x * MB;
    const int srow = tid >> 4;
    const int cs   = tid & 15;

    idx_s[tid]       = nidx[n0 * DEG + tid];
    idx_s[512 + tid] = nidx[n0 * DEG + 512 + tid];
    {   bfrag z = {0, 0, 0, 0, 0, 0, 0, 0};
        reinterpret_cast<bfrag*>(hbuf[0])[tid] = z; }

    const int colw = wave * 16 + (lane & 15);
    bfrag wih[4][4], whh[4][4];
#pragma unroll
    for (int g = 0; g < 4; ++g) {
        const short* pih = wihb + (g * 128 + colw) * FF + (lane >> 4) * 8;
        const short* phh = whhb + (g * 128 + colw) * FF + (lane >> 4) * 8;
#pragma unroll
        for (int kt = 0; kt < 4; ++kt) {
            wih[g][kt] = *reinterpret_cast<const bfrag*>(pih + kt * 32);
            whh[g][kt] = *reinterpret_cast<const bfrag*>(phh + kt * 32);
        }
    }
    const float bi = biasg[colw];
    const float bf = biasg[128 + colw];
    const float bg = biasg[256 + colw];
    const float bo = biasg[384 + colw];
    const f32x4 bvi = {bi, bi, bi, bi};
    const f32x4 bvf = {bf, bf, bf, bf};
    const f32x4 bvg = {bg, bg, bg, bg};
    const f32x4 bvo = {bo, bo, bo, bo};

    __syncthreads();
    {
        const float4* p = reinterpret_cast<const float4*>(featf + idx_s[srow * DEG] * FF + cs * 8);
        int sb = (srow * 256 + cs * 16) ^ ((srow & 7) << 4);
        *reinterpret_cast<bfrag*>(reinterpret_cast<char*>(xbuf[0]) + sb) = pack8(p[0], p[1]);
    }
    __syncthreads();

    const int arow = lane & 15;
    const int asub = (lane >> 4) * 16;
    const int hr0  = (lane >> 4) * 4;
    const int swz  = (arow & 7) << 4;

    auto mm4 = [&](const char* p, int rbase, const bfrag (&W)[4][4],
                   f32x4& vi, f32x4& vf, f32x4& vg, f32x4& vo) {
        bfrag a[4];
#pragma unroll
        for (int kt = 0; kt < 4; ++kt)
            a[kt] = *reinterpret_cast<const bfrag*>(p + ((rbase * 256 + kt * 64 + asub) ^ swz));
#pragma unroll
        for (int kt = 0; kt < 4; ++kt) {
            vi = __builtin_amdgcn_mfma_f32_16x16x32_bf16(a[kt], W[0][kt], vi, 0, 0, 0);
            vf = __builtin_amdgcn_mfma_f32_16x16x32_bf16(a[kt], W[1][kt], vf, 0, 0, 0);
            vg = __builtin_amdgcn_mfma_f32_16x16x32_bf16(a[kt], W[2][kt], vg, 0, 0, 0);
            vo = __builtin_amdgcn_mfma_f32_16x16x32_bf16(a[kt], W[3][kt], vo, 0, 0, 0);
        }
    };
    auto actw = [&](f32x4& gi, f32x4& gf, f32x4& gg, f32x4& go,
                    f32x4& cst, char* hnxt, int rt) {
#pragma unroll
        for (int r = 0; r < 4; ++r) {
            float av = __builtin_amdgcn_exp2f(-K1 * gi[r]);
            float bv = __builtin_amdgcn_exp2f(K2 * fminf(gg[r], 40.0f));
            float dv = __builtin_amdgcn_exp2f(-K1 * gf[r]);
            float ev = __builtin_amdgcn_exp2f(-K1 * go[r]);
            float t1 = __builtin_amdgcn_rcpf((1.0f + av) * (1.0f + bv));
            float t2 = __builtin_amdgcn_rcpf(1.0f + dv);
            float c  = fmaf(cst[r], t2, (bv - 1.0f) * t1);
            cst[r] = c;
            float uv = __builtin_amdgcn_exp2f(K2 * c);
            float t3 = __builtin_amdgcn_rcpf((1.0f + ev) * (1.0f + uv));
            float h  = (uv - 1.0f) * t3;
            int hrow = rt * 16 + hr0 + r;
            int hb   = (hrow * 256 + colw * 2) ^ ((hrow & 7) << 4);
            *reinterpret_cast<unsigned short*>(hnxt + hb) = b16(h);
        }
    };

    f32x4 p0i, p0f, p0g, p0o, p1i, p1f, p1g, p1o;
    {
        char* x0p = reinterpret_cast<char*>(xbuf[0]);
        p0i = bvi; p0f = bvf; p0g = bvg; p0o = bvo;
        mm4(x0p, arow, wih, p0i, p0f, p0g, p0o);
        p1i = bvi; p1f = bvf; p1g = bvg; p1o = bvo;
        mm4(x0p, 16 + arow, wih, p1i, p1f, p1g, p1o);
    }
    {
        const float4* p = reinterpret_cast<const float4*>(featf + idx_s[srow * DEG + 1] * FF + cs * 8);
        int sb = (srow * 256 + cs * 16) ^ ((srow & 7) << 4);
        *reinterpret_cast<bfrag*>(reinterpret_cast<char*>(xbuf[1]) + sb) = pack8(p[0], p[1]);
    }
    __syncthreads();

    const f32x4 zz = {0.f, 0.f, 0.f, 0.f};
    f32x4 cs0 = zz, cs1 = zz;

#pragma unroll 2
    for (int t = 0; t < DEG; ++t) {
        const int cur = t & 1;
        char* hcur = reinterpret_cast<char*>(hbuf[cur]);
        char* hnxt = reinterpret_cast<char*>(hbuf[cur ^ 1]);
        char* xrd  = reinterpret_cast<char*>(xbuf[cur ^ 1]);
        char* xwr  = reinterpret_cast<char*>(xbuf[cur]);

        bfrag pre2;
        if (t < DEG - 2) {
            const float4* p = reinterpret_cast<const float4*>(featf + idx_s[srow * DEG + t + 2] * FF + cs * 8);
            pre2 = pack8(p[0], p[1]);
        }
        {
            f32x4 gi = p0i, gf = p0f, gg = p0g, go = p0o;
            mm4(hcur, arow, whh, gi, gf, gg, go);
            if (t < DEG - 1) {
                p0i = bvi; p0f = bvf; p0g = bvg; p0o = bvo;
                mm4(xrd, arow, wih, p0i, p0f, p0g, p0o);
            }
            actw(gi, gf, gg, go, cs0, hnxt, 0);
        }
        {
            f32x4 gi = p1i, gf = p1f, gg = p1g, go = p1o;
            mm4(hcur, 16 + arow, whh, gi, gf, gg, go);
            if (t < DEG - 1) {
                p1i = bvi; p1f = bvf; p1g = bvg; p1o = bvo;
                mm4(xrd, 16 + arow, wih, p1i, p1f, p1g, p1o);
            }
            actw(gi, gf, gg, go, cs1, hnxt, 1);
        }
        if (t < DEG - 2) {
            int sb = (srow * 256 + cs * 16) ^ ((srow & 7) << 4);
            *reinterpret_cast<bfrag*>(xwr + sb) = pre2;
        }
        __syncthreads();
    }

    {
        const float4* p = reinterpret_cast<const float4*>(featf + (n0 + srow) * FF + cs * 8);
        int sb = (srow * 256 + cs * 16) ^ ((srow & 7) << 4);
        *reinterpret_cast<bfrag*>(reinterpret_cast<char*>(xbuf[0]) + sb) = pack8(p[0], p[1]);
    }
    __syncthreads();

    char* const x0p = reinterpret_cast<char*>(xbuf[0]);
    char* const h0p = reinterpret_cast<char*>(hbuf[0]);
    bfrag w1f[4], w2f[4];
#pragma unroll
    for (int kt = 0; kt < 4; ++kt) {
        w1f[kt] = *reinterpret_cast<const bfrag*>(w1b + colw * FF + kt * 32 + (lane >> 4) * 8);
        w2f[kt] = *reinterpret_cast<const bfrag*>(w2b + colw * FF + kt * 32 + (lane >> 4) * 8);
    }
    const float bb = biaso[colw];
#pragma unroll
    for (int rt = 0; rt < 2; ++rt) {
        bfrag fa[4], hfa[4];
#pragma unroll
        for (int kt = 0; kt < 4; ++kt) {
            int byte = ((rt * 16 + arow) * 256 + kt * 64 + asub) ^ swz;
            fa[kt]  = *reinterpret_cast<const bfrag*>(x0p + byte);
            hfa[kt] = *reinterpret_cast<const bfrag*>(h0p + byte);
        }
        f32x4 acc = {0.f, 0.f, 0.f, 0.f};
#pragma unroll
        for (int kt = 0; kt < 4; ++kt) {
            acc = __builtin_amdgcn_mfma_f32_16x16x32_bf16(fa[kt],  w1f[kt], acc, 0, 0, 0);
            acc = __builtin_amdgcn_mfma_f32_16x16x32_bf16(hfa[kt], w2f[kt], acc, 0, 0, 0);
        }
#pragma unroll
        for (int r = 0; r < 4; ++r) {
            int orow = n0 + rt * 16 + hr0 + r;
            out[orow * OO + colw] = acc[r] + bb;
        }
    }
}

extern "C" void kernel_launch(void* const* d_in, const int* in_sizes, int n_in,
                              void* d_out, int out_size, void* d_ws, size_t ws_size,
                              hipStream_t stream)
{
    const float* feat = (const float*)d_in[0];
    const int*   nidx = (const int*)d_in[1];
    const float* W_ih = (const float*)d_in[2];
    const float* W_hh = (const float*)d_in[3];
    const float* b_ih = (const float*)d_in[4];
    const float* b_hh = (const float*)d_in[5];
    const float* W1   = (const float*)d_in[6];
    const float* b1   = (const float*)d_in[7];
    const float* W2   = (const float*)d_in[8];
    const float* b2   = (const float*)d_in[9];
    float* out = (float*)d_out;

    char* ws = (char*)d_ws;
    short* wihb  = (short*)(ws);             // 131072 B
    short* whhb  = (short*)(ws + 131072);    // 131072 B
    short* w1b   = (short*)(ws + 262144);    // 32768 B
    short* w2b   = (short*)(ws + 294912);    // 32768 B
    float* biasg = (float*)(ws + 327680);    // 2048 B
    float* biaso = (float*)(ws + 329728);    // 512 B
    unsigned short* xpb = (unsigned short*)(ws + 330240);   // 33554432 B

    const size_t need = 330240 + (size_t)NN * 512 * 2;

    prep_weights<<<256, 256, 0, stream>>>(W_ih, W_hh, b_ih, b_hh, W1, b1, W2, b2,
                                          wihb, whhb, w1b, w2b, biasg, biaso);
    if (ws_size >= need) {
        xp_gemm<<<NN / MB, 512, 0, stream>>>(feat, wihb, biasg, xpb);
        sage_xp3<<<NN / MB2, 256, 0, stream>>>(feat, nidx, xpb, whhb, w1b, w2b, biaso, out);
    } else {
        sage_lstm_fb<<<NN / MB, 512, 0, stream>>>(feat, nidx, wihb, whhb,
                                                  w1b, w2b, biasg, biaso, out);
    }
}